// Round 6
// baseline (722.210 us; speedup 1.0000x reference)
//
#include <hip/hip_runtime.h>

// Problem constants (from reference)
#define N_ITEMS     100000
#define EMBED_DIM   64
#define N_REL       3
#define N_EDGES     3200000
#define TOTAL_EDGES (N_REL * N_EDGES)   // 9,600,000 (fits int)
#define NKEY        (N_REL * N_ITEMS)   // 300,000 (v5 fallback)

// ============ v14: single-pass XCD-affine scatter + proven fused gather ======
// Buckets: 64-row chunk x rel (4689). Each bucket has 8 per-XCD sub-regions so
// a given 64B line tail is only appended by blocks of one residue class
// (blockIdx&7 ~ XCD, round-robin dispatch) -> L2-local merge, no write amp.
// Capacity is mapping-independent: class k handles exactly 1/8 of edges.
#define LOG_CH   6
#define CH_ROWS  64
#define NCHUNK   1563                       // ceil(100000/64)
#define NBKT     (NCHUNK * N_REL)           // 4689
#define NSUB     8
#define SUBCAP   384                        // mean 256 + 8.5 sigma
#define BSTRIDE  (NSUB * SUBCAP)            // 3072 slots per bucket region
#define NCUR     (NBKT * NSUB)              // 37512 cursors
#define SRTCAP   2432                       // mean 2048 + 8.5 sigma (per bucket)

// ---- v14.1: fused init (37512 cursors) + vectorized E -> bf16 ----
__global__ void init14_kernel(const float* __restrict__ E,
                              unsigned short* __restrict__ Ebf,
                              unsigned* __restrict__ cur) {
    int i = blockIdx.x * 256 + threadIdx.x;
    if (i < NCUR) {
        unsigned b = (unsigned)i >> 3, x = (unsigned)i & 7u;
        cur[i] = b * (unsigned)BSTRIDE + x * (unsigned)SUBCAP;
    }
    if (i < N_ITEMS * 16) {                 // 4 floats -> 4 bf16 per thread
        float4 f = ((const float4*)E)[i];
        unsigned u0 = __float_as_uint(f.x), u1 = __float_as_uint(f.y);
        unsigned u2 = __float_as_uint(f.z), u3 = __float_as_uint(f.w);
        ushort4 o;
        o.x = (unsigned short)((u0 + 0x7FFFu + ((u0 >> 16) & 1u)) >> 16);  // RNE
        o.y = (unsigned short)((u1 + 0x7FFFu + ((u1 >> 16) & 1u)) >> 16);
        o.z = (unsigned short)((u2 + 0x7FFFu + ((u2 >> 16) & 1u)) >> 16);
        o.w = (unsigned short)((u3 + 0x7FFFu + ((u3 >> 16) & 1u)) >> 16);
        ((ushort4*)Ebf)[i] = o;
    }
}

// ---- v14.2: single-pass scatter into per-XCD sub-buckets ----
// rec: x = col(17b) | lrow6 << 17 ; y = val bits. (rel implied by bucket)
__launch_bounds__(256)
__global__ void binscatter_xcd_kernel(const int* __restrict__ rows,
                                      const int* __restrict__ cols,
                                      const float* __restrict__ vals,
                                      unsigned* __restrict__ cur,
                                      uint2* __restrict__ recs) {
    unsigned cls = (unsigned)blockIdx.x & 7u;
    int stride = gridDim.x * blockDim.x;
    for (int i = blockIdx.x * blockDim.x + threadIdx.x; i < TOTAL_EDGES; i += stride) {
        unsigned rel = (unsigned)i / (unsigned)N_EDGES;
        unsigned row = (unsigned)rows[i];
        unsigned b = (row >> LOG_CH) * 3u + rel;
        unsigned pos = atomicAdd(&cur[(b << 3) + cls], 1u);
        if (pos < b * (unsigned)BSTRIDE + cls * (unsigned)SUBCAP + (unsigned)SUBCAP)
            recs[pos] = make_uint2((unsigned)cols[i] | ((row & 63u) << 17),
                                   __float_as_uint(vals[i]));
    }
}

// ---- v14.3: fused count-sort + gather (v12-proven phases; 8-seg staging) ----
__launch_bounds__(512, 8)
__global__ void gather_sort_kernel(const uint2* __restrict__ Ebf4,   // ushort4 rows viewed as uint2
                                   const float* __restrict__ E,
                                   const unsigned* __restrict__ cur,
                                   const uint2* __restrict__ recs,
                                   float* __restrict__ out) {
    __shared__ uint2  srt[SRTCAP];               // 19.0 KB sorted records
    __shared__ float4 accT4[CH_ROWS * 16];       // 16 KB fp32 accumulation tile
    __shared__ unsigned hist[CH_ROWS], curh[CH_ROWS], rstart[CH_ROWS + 1], sp[9];
    int c = blockIdx.x;
    int t = threadIdx.x;
    int w = t >> 6;            // wave 0..7 -> owns rows 8w..8w+7
    int lane = t & 63;
    int sub = lane >> 4;       // edge substream 0..3
    int q = lane & 15;         // dim quad (4q..4q+3)

    float* accT = (float*)accT4;
    for (int k = t; k < CH_ROWS * EMBED_DIM; k += 512) accT[k] = 0.f;

    for (int rel = 0; rel < N_REL; rel++) {
        unsigned b = (unsigned)(c * N_REL + rel);
        unsigned bb = b * (unsigned)BSTRIDE;
        // ---- 8 sub-segment lengths -> prefix sp[0..8] ----
        if (t < 8) {
            unsigned len = cur[(b << 3) + (unsigned)t] - (bb + (unsigned)t * SUBCAP);
            if (len > (unsigned)SUBCAP) len = (unsigned)SUBCAP;
            sp[t + 1] = len;
        }
        if (t == 0) sp[0] = 0u;
        __syncthreads();
        if (t == 0) {
            unsigned run = 0;
            #pragma unroll
            for (int s = 1; s <= 8; s++) {
                run += sp[s];
                if (run > (unsigned)SRTCAP) run = (unsigned)SRTCAP;
                sp[s] = run;
            }
        }
        __syncthreads();
        int n = (int)sp[8];

        // register-stage this bucket's records (virtual concat over 8 segs)
        uint2 rc[5];
        #pragma unroll
        for (int k = 0; k < 5; k++) {
            int i = t + (k << 9);
            if (i < n) {
                unsigned s = 0;
                #pragma unroll
                for (int j = 1; j <= 7; j++) s += ((unsigned)i >= sp[j]) ? 1u : 0u;
                rc[k] = recs[bb + s * (unsigned)SUBCAP + ((unsigned)i - sp[s])];
            } else rc[k] = make_uint2(0u, 0u);
        }
        if (t < CH_ROWS) hist[t] = 0u;
        __syncthreads();
        #pragma unroll
        for (int k = 0; k < 5; k++) {
            int i = t + (k << 9);
            if (i < n) atomicAdd(&hist[rc[k].x >> 17], 1u);
        }
        __syncthreads();
        if (t < 64) {                            // wave 0: exclusive scan of 64 bins
            unsigned v = hist[t];
            unsigned inc = v;
            #pragma unroll
            for (int d = 1; d < 64; d <<= 1) {
                unsigned x = __shfl_up(inc, d, 64);
                if (lane >= d) inc += x;
            }
            rstart[t] = inc - v;
            curh[t] = inc - v;
            if (t == 63) rstart[64] = inc;
        }
        __syncthreads();
        #pragma unroll
        for (int k = 0; k < 5; k++) {            // sort-scatter from registers
            int i = t + (k << 9);
            if (i < n) {
                unsigned pos = atomicAdd(&curh[rc[k].x >> 17], 1u);
                srt[pos] = make_uint2(rc[k].x & 0x1FFFFu, rc[k].y);
            }
        }
        __syncthreads();

        // ---- per-row register gather (R0-proven 16-lane x 4-substream, 4-deep) ----
        for (int k = 0; k < 8; k++) {
            int r = (w << 3) + k;
            int base = (int)rstart[r];
            int nr = (int)(rstart[r + 1] - rstart[r]);
            float a0 = 0.f, a1 = 0.f, a2 = 0.f, a3 = 0.f, dg = 0.f;
            int i = sub;
            for (; i + 12 < nr; i += 16) {       // 4 edges in flight per substream
                uint2 r0 = srt[base + i],     r1 = srt[base + i + 4];
                uint2 r2 = srt[base + i + 8], r3 = srt[base + i + 12];
                uint2 e0 = Ebf4[r0.x * 16u + q];
                uint2 e1 = Ebf4[r1.x * 16u + q];
                uint2 e2 = Ebf4[r2.x * 16u + q];
                uint2 e3 = Ebf4[r3.x * 16u + q];
                float w0 = __uint_as_float(r0.y), w1 = __uint_as_float(r1.y);
                float w2 = __uint_as_float(r2.y), w3 = __uint_as_float(r3.y);
                a0 += w0 * __uint_as_float(e0.x << 16);
                a1 += w0 * __uint_as_float(e0.x & 0xFFFF0000u);
                a2 += w0 * __uint_as_float(e0.y << 16);
                a3 += w0 * __uint_as_float(e0.y & 0xFFFF0000u);
                dg += w0;
                a0 += w1 * __uint_as_float(e1.x << 16);
                a1 += w1 * __uint_as_float(e1.x & 0xFFFF0000u);
                a2 += w1 * __uint_as_float(e1.y << 16);
                a3 += w1 * __uint_as_float(e1.y & 0xFFFF0000u);
                dg += w1;
                a0 += w2 * __uint_as_float(e2.x << 16);
                a1 += w2 * __uint_as_float(e2.x & 0xFFFF0000u);
                a2 += w2 * __uint_as_float(e2.y << 16);
                a3 += w2 * __uint_as_float(e2.y & 0xFFFF0000u);
                dg += w2;
                a0 += w3 * __uint_as_float(e3.x << 16);
                a1 += w3 * __uint_as_float(e3.x & 0xFFFF0000u);
                a2 += w3 * __uint_as_float(e3.y << 16);
                a3 += w3 * __uint_as_float(e3.y & 0xFFFF0000u);
                dg += w3;
            }
            for (; i < nr; i += 4) {
                uint2 r0 = srt[base + i];
                uint2 e0 = Ebf4[r0.x * 16u + q];
                float w0 = __uint_as_float(r0.y);
                a0 += w0 * __uint_as_float(e0.x << 16);
                a1 += w0 * __uint_as_float(e0.x & 0xFFFF0000u);
                a2 += w0 * __uint_as_float(e0.y << 16);
                a3 += w0 * __uint_as_float(e0.y & 0xFFFF0000u);
                dg += w0;
            }
            // combine 4 substreams (lanes differing in bits 4,5)
            a0 += __shfl_xor(a0, 16, 64);  a0 += __shfl_xor(a0, 32, 64);
            a1 += __shfl_xor(a1, 16, 64);  a1 += __shfl_xor(a1, 32, 64);
            a2 += __shfl_xor(a2, 16, 64);  a2 += __shfl_xor(a2, 32, 64);
            a3 += __shfl_xor(a3, 16, 64);  a3 += __shfl_xor(a3, 32, 64);
            dg += __shfl_xor(dg, 16, 64);  dg += __shfl_xor(dg, 32, 64);
            float inv = 1.0f / (3.0f * fmaxf(dg, 1.0f));
            if (sub == 0) {                      // exclusive owner: plain RMW
                float4 o = accT4[(r << 4) + q];
                accT4[(r << 4) + q] = make_float4(o.x + a0 * inv, o.y + a1 * inv,
                                                  o.z + a2 * inv, o.w + a3 * inv);
            }
        }
        __syncthreads();                         // srt/hist reuse next rel
    }

    int gbase2 = c * (CH_ROWS * EMBED_DIM);
    for (int k = t; k < CH_ROWS * EMBED_DIM; k += 512) {
        int gi = gbase2 + k;
        if (gi < N_ITEMS * EMBED_DIM) out[gi] = E[gi] + accT[k];
    }
}

// ============================ v5 fallback (R5 pipeline) ============================
#define NBS ((NKEY + 255) / 256)

__global__ void hist300_kernel(const int* __restrict__ rows, unsigned* __restrict__ cnt) {
    int stride = gridDim.x * blockDim.x;
    for (int i = blockIdx.x * blockDim.x + threadIdx.x; i < TOTAL_EDGES; i += stride) {
        unsigned r = (unsigned)i / (unsigned)N_EDGES;
        unsigned key = r * N_ITEMS + (unsigned)rows[i];
        atomicAdd(&cnt[key], 1u);
    }
}

__global__ void scan_blocksum(const unsigned* __restrict__ cnt, unsigned* __restrict__ bsum) {
    __shared__ unsigned s[256];
    int i = blockIdx.x * 256 + threadIdx.x;
    s[threadIdx.x] = (i < NKEY) ? cnt[i] : 0u;
    __syncthreads();
    for (int off = 128; off > 0; off >>= 1) {
        if (threadIdx.x < off) s[threadIdx.x] += s[threadIdx.x + off];
        __syncthreads();
    }
    if (threadIdx.x == 0) bsum[blockIdx.x] = s[0];
}

__global__ void scan_partials(unsigned* __restrict__ bsum, unsigned* __restrict__ starts) {
    const int IT = 5;
    int t = threadIdx.x;
    unsigned loc[IT];
    unsigned sum = 0;
    #pragma unroll
    for (int k = 0; k < IT; k++) {
        int idx = t * IT + k;
        loc[k] = (idx < NBS) ? bsum[idx] : 0u;
        sum += loc[k];
    }
    int lane = t & 63, wid = t >> 6;
    unsigned inc = sum;
    #pragma unroll
    for (int d = 1; d < 64; d <<= 1) {
        unsigned x = __shfl_up(inc, d, 64);
        if (lane >= d) inc += x;
    }
    __shared__ unsigned woff[4], woffEx[4];
    if (lane == 63) woff[wid] = inc;
    __syncthreads();
    if (t == 0) { unsigned run = 0; for (int k = 0; k < 4; k++) { woffEx[k] = run; run += woff[k]; } }
    __syncthreads();
    unsigned ex = inc - sum + woffEx[wid];
    #pragma unroll
    for (int k = 0; k < IT; k++) {
        int idx = t * IT + k;
        if (idx < NBS) { bsum[idx] = ex; ex += loc[k]; }
    }
    if (t == 0) starts[NKEY] = (unsigned)TOTAL_EDGES;
}

__global__ void scan_final(unsigned* key_arr,
                           const unsigned* __restrict__ bsum,
                           unsigned* __restrict__ cursor) {
    int i = blockIdx.x * 256 + threadIdx.x;
    unsigned v = (i < NKEY) ? key_arr[i] : 0u;
    int lane = threadIdx.x & 63, wid = threadIdx.x >> 6;
    unsigned inc = v;
    #pragma unroll
    for (int d = 1; d < 64; d <<= 1) {
        unsigned x = __shfl_up(inc, d, 64);
        if (lane >= d) inc += x;
    }
    __shared__ unsigned woff[4], woffEx[4];
    if (lane == 63) woff[wid] = inc;
    __syncthreads();
    if (threadIdx.x == 0) { unsigned run = 0; for (int k = 0; k < 4; k++) { woffEx[k] = run; run += woff[k]; } }
    __syncthreads();
    unsigned ex = inc - v + woffEx[wid] + bsum[blockIdx.x];
    if (i < NKEY) { key_arr[i] = ex; cursor[i] = ex; }
}

__global__ void binscatter2_kernel(const int* __restrict__ rows,
                                   const int* __restrict__ cols,
                                   const float* __restrict__ vals,
                                   unsigned* __restrict__ cursor,
                                   uint2* __restrict__ recs) {
    int stride = gridDim.x * blockDim.x;
    for (int i = blockIdx.x * blockDim.x + threadIdx.x; i < TOTAL_EDGES; i += stride) {
        unsigned r = (unsigned)i / (unsigned)N_EDGES;
        unsigned key = r * N_ITEMS + (unsigned)rows[i];
        unsigned pos = atomicAdd(&cursor[key], 1u);
        uint2 rec;
        rec.x = (unsigned)cols[i];
        rec.y = __float_as_uint(vals[i]);
        recs[pos] = rec;
    }
}

__launch_bounds__(192)
__global__ void gather_csr_f32_kernel(const float* __restrict__ E,
                                      const unsigned* __restrict__ starts,
                                      const uint2* __restrict__ recs,
                                      float* __restrict__ out) {
    __shared__ float part[N_REL * EMBED_DIM];
    int row = blockIdx.x;
    int w = threadIdx.x >> 6;
    int d = threadIdx.x & 63;
    unsigned key = (unsigned)w * N_ITEMS + (unsigned)row;
    unsigned s = starts[key];
    int n = (int)(starts[key + 1] - s);
    const uint2* __restrict__ p = recs + s;
    float acc = 0.0f, deg = 0.0f;
    int j = 0;
    for (; j + 8 <= n; j += 8) {
        uint2 a[8];
        #pragma unroll
        for (int k = 0; k < 8; k++) a[k] = p[j + k];
        float e[8];
        #pragma unroll
        for (int k = 0; k < 8; k++) e[k] = E[a[k].x * EMBED_DIM + d];
        #pragma unroll
        for (int k = 0; k < 8; k++) {
            float wv = __uint_as_float(a[k].y);
            acc += wv * e[k];
            deg += wv;
        }
    }
    for (; j < n; j++) {
        uint2 a = p[j];
        float wv = __uint_as_float(a.y);
        acc += wv * E[a.x * EMBED_DIM + d];
        deg += wv;
    }
    part[w * EMBED_DIM + d] = acc / (3.0f * fmaxf(deg, 1.0f));
    __syncthreads();
    if (threadIdx.x < EMBED_DIM) {
        int gi = row * EMBED_DIM + threadIdx.x;
        out[gi] = E[gi] + part[threadIdx.x]
                        + part[EMBED_DIM + threadIdx.x]
                        + part[2 * EMBED_DIM + threadIdx.x];
    }
}

// ============================ R1 fallback ============================
__global__ void deg_kernel(const int* __restrict__ rows,
                           const float* __restrict__ vals,
                           float* __restrict__ deg) {
    long long i = (long long)blockIdx.x * blockDim.x + threadIdx.x;
    if (i >= TOTAL_EDGES) return;
    int r = (int)(i / N_EDGES);
    int row = rows[i];
    atomicAdd(&deg[(long long)r * N_ITEMS + row], vals[i]);
}

__global__ void inv_kernel(float* __restrict__ deg) {
    int i = blockIdx.x * blockDim.x + threadIdx.x;
    if (i >= N_REL * N_ITEMS) return;
    float d = deg[i];
    d = fmaxf(d, 1.0f);
    deg[i] = 1.0f / (3.0f * d);
}

__global__ void scatter_kernel(const float* __restrict__ E,
                               const int* __restrict__ rows,
                               const int* __restrict__ cols,
                               const float* __restrict__ vals,
                               const float* __restrict__ inv,
                               float* __restrict__ out) {
    long long t = (long long)blockIdx.x * blockDim.x + threadIdx.x;
    long long edge = t >> 6;
    int d = (int)(t & 63);
    if (edge >= TOTAL_EDGES) return;
    int r = (int)(edge / N_EDGES);
    int row = rows[edge];
    int col = cols[edge];
    float w = vals[edge] * inv[r * N_ITEMS + row];
    float msg = w * E[(long long)col * EMBED_DIM + d];
    atomicAdd(&out[(long long)row * EMBED_DIM + d], msg);
}

// ============================ launcher ============================
extern "C" void kernel_launch(void* const* d_in, const int* in_sizes, int n_in,
                              void* d_out, int out_size, void* d_ws, size_t ws_size,
                              hipStream_t stream) {
    const float* E    = (const float*)d_in[0];
    const int*   rows = (const int*)d_in[1];
    const int*   cols = (const int*)d_in[2];
    const float* vals = (const float*)d_in[3];
    float* out = (float*)d_out;

    // v14 workspace: cur (37512 u32, padded) | recs (115.2 MB) | Ebf (12.8 MB)
    const size_t CURB   = 163840;
    const size_t RECB14 = (size_t)NBKT * BSTRIDE * sizeof(uint2);   // 115,236,864
    const size_t EBF_B  = (size_t)N_ITEMS * EMBED_DIM * 2;          // 12.8 MB
    size_t need14 = CURB + RECB14 + EBF_B;                          // ~128.2 MB (< proven 129.5)

    // v5 fallback sizes
    const size_t REGA = 1204224;                                    // >= (NKEY+1)*4
    const size_t REGC = 8192;
    const size_t RECB = (size_t)TOTAL_EDGES * sizeof(uint2);        // 76.8 MB
    size_t need5 = 2 * REGA + REGC + RECB;

    if (ws_size >= need14) {
        unsigned* cur  = (unsigned*)d_ws;
        uint2*    recs = (uint2*)((char*)d_ws + CURB);
        unsigned short* Ebf = (unsigned short*)((char*)d_ws + CURB + RECB14);

        init14_kernel<<<(N_ITEMS * 16 + 255) / 256, 256, 0, stream>>>(E, Ebf, cur);
        binscatter_xcd_kernel<<<2048, 256, 0, stream>>>(rows, cols, vals, cur, recs);
        gather_sort_kernel<<<NCHUNK, 512, 0, stream>>>((const uint2*)Ebf, E, cur, recs, out);
    } else if (ws_size >= need5) {
        unsigned* keyA   = (unsigned*)d_ws;
        unsigned* cursor = (unsigned*)((char*)d_ws + REGA);
        unsigned* bsum   = (unsigned*)((char*)d_ws + 2 * REGA);
        uint2*    recs   = (uint2*)((char*)d_ws + 2 * REGA + REGC);

        hipMemsetAsync(keyA, 0, NKEY * sizeof(unsigned), stream);
        hist300_kernel<<<1536, 256, 0, stream>>>(rows, keyA);
        scan_blocksum<<<NBS, 256, 0, stream>>>(keyA, bsum);
        scan_partials<<<1, 256, 0, stream>>>(bsum, keyA);
        scan_final<<<NBS, 256, 0, stream>>>(keyA, bsum, cursor);
        binscatter2_kernel<<<2048, 256, 0, stream>>>(rows, cols, vals, cursor, recs);
        gather_csr_f32_kernel<<<N_ITEMS, 192, 0, stream>>>(E, keyA, recs, out);
    } else {
        float* deg = (float*)d_ws;
        hipMemsetAsync(deg, 0, (size_t)N_REL * N_ITEMS * sizeof(float), stream);
        {
            long long total = TOTAL_EDGES;
            int block = 256;
            long long grid = (total + block - 1) / block;
            deg_kernel<<<(unsigned)grid, block, 0, stream>>>(rows, vals, deg);
        }
        {
            int total = N_REL * N_ITEMS;
            int block = 256;
            int grid = (total + block - 1) / block;
            inv_kernel<<<grid, block, 0, stream>>>(deg);
        }
        hipMemcpyAsync(out, E, (size_t)N_ITEMS * EMBED_DIM * sizeof(float),
                       hipMemcpyDeviceToDevice, stream);
        {
            long long threads = (long long)TOTAL_EDGES * 64;
            int block = 256;
            long long grid = (threads + block - 1) / block;
            scatter_kernel<<<(unsigned)grid, block, 0, stream>>>(E, rows, cols, vals, deg, out);
        }
    }
}

// Round 7
// 441.308 us; speedup vs baseline: 1.6365x; 1.6365x over previous
//
#include <hip/hip_runtime.h>

// Problem constants (from reference)
#define N_ITEMS     100000
#define EMBED_DIM   64
#define N_REL       3
#define N_EDGES     3200000
#define TOTAL_EDGES (N_REL * N_EDGES)   // 9,600,000 (fits int)
#define NKEY        (N_REL * N_ITEMS)   // 300,000 (v5 fallback)

// ====== v15: 8-blocks/CU staged two-level partition + v12-proven gather ======
// Fine buckets (gather granularity): 64-row chunk x rel, capacity slots.
#define LOG_CH   6
#define CH_ROWS  64
#define NCHUNK   1563                       // ceil(100000/64)
#define NBKT     (NCHUNK * N_REL)           // 4689
#define BCAP     2368                       // mean 2048 + ~7 sigma (proven R2-R5)
// Coarse buckets: 4096-row chunks; cursors RELATIVE to each rel's region.
#define LOG_CB   12
#define NCB      25                         // ceil(100000/4096)
#define TILEP    1024                       // staged tile (8KB+1KB LDS) -> 8 blk/CU
#define NTILEP   (N_EDGES / TILEP)          // 3125 (exact)
#define SEGSB    136
#define CBCAP    (SEGSB * TILEP)            // 139264 = mean 131072 + slack (proven)

// ---- v15.1: fused init (cursors) + vectorized E -> bf16 ----
__global__ void init15_kernel(const float* __restrict__ E,
                              unsigned short* __restrict__ Ebf,
                              unsigned* __restrict__ gcursorF,
                              unsigned* __restrict__ cursorC) {
    int i = blockIdx.x * 256 + threadIdx.x;
    if (i < NBKT) gcursorF[i] = (unsigned)i * (unsigned)BCAP;
    if (i < N_REL * NCB) cursorC[i] = (unsigned)(i % NCB) * (unsigned)CBCAP;
    if (i < N_ITEMS * 16) {                 // 4 floats -> 4 bf16 per thread
        float4 f = ((const float4*)E)[i];
        unsigned u0 = __float_as_uint(f.x), u1 = __float_as_uint(f.y);
        unsigned u2 = __float_as_uint(f.z), u3 = __float_as_uint(f.w);
        ushort4 o;
        o.x = (unsigned short)((u0 + 0x7FFFu + ((u0 >> 16) & 1u)) >> 16);  // RNE
        o.y = (unsigned short)((u1 + 0x7FFFu + ((u1 >> 16) & 1u)) >> 16);
        o.z = (unsigned short)((u2 + 0x7FFFu + ((u2 >> 16) & 1u)) >> 16);
        o.w = (unsigned short)((u3 + 0x7FFFu + ((u3 >> 16) & 1u)) >> 16);
        ((ushort4*)Ebf)[i] = o;
    }
}

// ---- v15.2 pass A: 256-thr/4-edge reg-staged partition into 25 coarse buckets ----
// coarse rec: x = col(17b) | lrow12 << 17 ; y = val bits.
__launch_bounds__(256, 8)
__global__ void partA4_kernel(const int* __restrict__ rows,
                              const int* __restrict__ cols,
                              const float* __restrict__ vals,
                              unsigned* __restrict__ cursorC,
                              uint2* __restrict__ coarse,
                              int rel0, unsigned relStrideU2) {
    __shared__ uint2 stag[TILEP];              // 8 KB
    __shared__ unsigned char bkt[TILEP];       // 1 KB
    __shared__ unsigned hist[NCB], lstart[NCB], gbase[NCB], lcur[NCB];
    int rel = rel0 + blockIdx.x / NTILEP;
    int base = (blockIdx.x % NTILEP) * TILEP;
    int t = threadIdx.x;
    const int go = rel * N_EDGES + base;
    uint2* __restrict__ coarseRel = coarse + (size_t)(rel - rel0) * relStrideU2;

    unsigned rrow[4], rcol[4], rval[4];
    #pragma unroll
    for (int k = 0; k < 4; k++) {
        int i = t + (k << 8);
        rrow[k] = (unsigned)rows[go + i];
        rcol[k] = (unsigned)cols[go + i];
        rval[k] = __float_as_uint(vals[go + i]);
    }
    if (t < NCB) hist[t] = 0u;
    __syncthreads();
    #pragma unroll
    for (int k = 0; k < 4; k++) atomicAdd(&hist[rrow[k] >> LOG_CB], 1u);
    __syncthreads();
    if (t < 32) {                              // wave-parallel scan of 25 bins
        unsigned v = (t < NCB) ? hist[t] : 0u;
        unsigned inc = v;
        #pragma unroll
        for (int d = 1; d < 32; d <<= 1) {
            unsigned x = __shfl_up(inc, d, 32);
            if (t >= d) inc += x;
        }
        if (t < NCB) {
            unsigned ex = inc - v;
            lstart[t] = ex; lcur[t] = ex;
            if (v) gbase[t] = atomicAdd(&cursorC[rel * NCB + t], v);
        }
    }
    __syncthreads();
    #pragma unroll
    for (int k = 0; k < 4; k++) {
        unsigned row = rrow[k];
        unsigned cb = row >> LOG_CB;
        unsigned dst = atomicAdd(&lcur[cb], 1u);
        stag[dst] = make_uint2(rcol[k] | ((row & 4095u) << 17), rval[k]);
        bkt[dst] = (unsigned char)cb;
    }
    __syncthreads();
    // flush: consecutive staged slots of a bucket -> consecutive global slots
    for (int i = t; i < TILEP; i += 256) {
        unsigned bb = bkt[i];
        unsigned dst = gbase[bb] + ((unsigned)i - lstart[bb]);
        if (dst < (bb + 1u) * (unsigned)CBCAP) coarseRel[dst] = stag[i];
    }
}

// ---- v15.3 pass B: 256-thr/4-edge reg-staged refine into 64 fine buckets ----
// fine rec: x = col(17b) | lrow6 << 17 ; y = val bits.
__launch_bounds__(256, 8)
__global__ void partB4_kernel(const unsigned* __restrict__ cursorC,
                              const uint2* __restrict__ coarse,
                              unsigned* __restrict__ gcursorF,
                              uint2* __restrict__ recs,
                              int rel0, unsigned relStrideU2) {
    __shared__ uint2 stag[TILEP];              // 8 KB
    __shared__ unsigned char bkt[TILEP];       // 1 KB
    __shared__ unsigned hist[64], lstart[64], gbase[64], lcur[64];
    int rel = rel0 + blockIdx.x / (NCB * SEGSB);
    int rem = blockIdx.x % (NCB * SEGSB);
    int cb = rem / SEGSB, seg = rem % SEGSB;
    unsigned cntA = cursorC[rel * NCB + cb] - (unsigned)cb * (unsigned)CBCAP;
    if (cntA > (unsigned)CBCAP) cntA = (unsigned)CBCAP;
    int off = seg * TILEP;
    int cnt = (int)cntA - off;
    if (cnt <= 0) return;                      // block-uniform: no divergent barrier
    if (cnt > TILEP) cnt = TILEP;
    const uint2* __restrict__ src = coarse + (size_t)(rel - rel0) * relStrideU2
                                  + (unsigned)cb * (unsigned)CBCAP + off;
    int t = threadIdx.x;

    uint2 rc[4];
    #pragma unroll
    for (int k = 0; k < 4; k++) {
        int i = t + (k << 8);
        rc[k] = (i < cnt) ? src[i] : make_uint2(0xFFFFFFFFu, 0u);
    }
    if (t < 64) hist[t] = 0u;
    __syncthreads();
    #pragma unroll
    for (int k = 0; k < 4; k++)
        if (rc[k].x != 0xFFFFFFFFu) atomicAdd(&hist[(rc[k].x >> 23) & 63u], 1u);
    __syncthreads();
    if (t < 64) {                              // wave0: full shfl scan of 64 bins
        unsigned v = hist[t];
        unsigned inc = v;
        #pragma unroll
        for (int d = 1; d < 64; d <<= 1) {
            unsigned x = __shfl_up(inc, d, 64);
            if (t >= d) inc += x;
        }
        unsigned ex = inc - v;
        lstart[t] = ex; lcur[t] = ex;
        if (v) gbase[t] = atomicAdd(&gcursorF[(((unsigned)cb << 6) + t) * 3u + rel], v);
    }
    __syncthreads();
    #pragma unroll
    for (int k = 0; k < 4; k++)
        if (rc[k].x != 0xFFFFFFFFu) {
            unsigned j = (rc[k].x >> 23) & 63u;
            unsigned dst = atomicAdd(&lcur[j], 1u);
            stag[dst] = make_uint2(rc[k].x & 0x7FFFFFu, rc[k].y);
            bkt[dst] = (unsigned char)j;
        }
    __syncthreads();
    for (int i = t; i < cnt; i += 256) {
        unsigned j = bkt[i];
        unsigned bf = (((unsigned)cb << 6) + j) * 3u + rel;
        unsigned dst = gbase[j] + ((unsigned)i - lstart[j]);
        if (dst < (bf + 1u) * (unsigned)BCAP) recs[dst] = stag[i];
    }
}

// ---- v15.4: fused count-sort + gather — BYTE-IDENTICAL to v12 (proven 162 µs) ----
__launch_bounds__(512, 8)
__global__ void gather_sort_kernel(const uint2* __restrict__ Ebf4,   // ushort4 rows viewed as uint2
                                   const float* __restrict__ E,
                                   const unsigned* __restrict__ gcursorF,
                                   const uint2* __restrict__ recs,
                                   float* __restrict__ out) {
    __shared__ uint2  srt[BCAP];                 // 18.5 KB sorted records
    __shared__ float4 accT4[CH_ROWS * 16];       // 16 KB fp32 accumulation tile
    __shared__ unsigned hist[CH_ROWS], cur[CH_ROWS], rstart[CH_ROWS + 1];
    int c = blockIdx.x;
    int t = threadIdx.x;
    int w = t >> 6;            // wave 0..7 -> owns rows 8w..8w+7
    int lane = t & 63;
    int sub = lane >> 4;       // edge substream 0..3
    int q = lane & 15;         // dim quad (4q..4q+3)

    float* accT = (float*)accT4;
    for (int k = t; k < CH_ROWS * EMBED_DIM; k += 512) accT[k] = 0.f;

    for (int rel = 0; rel < N_REL; rel++) {
        unsigned b = (unsigned)(c * N_REL + rel);
        unsigned s0 = b * (unsigned)BCAP;
        int n = (int)(gcursorF[b] - s0);
        if (n > BCAP) n = BCAP;
        const uint2* __restrict__ pg = recs + s0;

        // register-stage this bucket's records (single global read)
        uint2 rc[5];
        #pragma unroll
        for (int k = 0; k < 5; k++) {
            int i = t + (k << 9);
            rc[k] = (i < n) ? pg[i] : make_uint2(0u, 0u);
        }
        if (t < CH_ROWS) hist[t] = 0u;
        __syncthreads();
        #pragma unroll
        for (int k = 0; k < 5; k++) {
            int i = t + (k << 9);
            if (i < n) atomicAdd(&hist[rc[k].x >> 17], 1u);
        }
        __syncthreads();
        if (t < 64) {                            // wave 0: exclusive scan of 64 bins
            unsigned v = hist[t];
            unsigned inc = v;
            #pragma unroll
            for (int d = 1; d < 64; d <<= 1) {
                unsigned x = __shfl_up(inc, d, 64);
                if (lane >= d) inc += x;
            }
            rstart[t] = inc - v;
            cur[t] = inc - v;
            if (t == 63) rstart[64] = inc;
        }
        __syncthreads();
        #pragma unroll
        for (int k = 0; k < 5; k++) {            // sort-scatter from registers
            int i = t + (k << 9);
            if (i < n) {
                unsigned pos = atomicAdd(&cur[rc[k].x >> 17], 1u);
                srt[pos] = make_uint2(rc[k].x & 0x1FFFFu, rc[k].y);
            }
        }
        __syncthreads();

        // ---- per-row register gather (R0-proven 16-lane x 4-substream, 4-deep) ----
        for (int k = 0; k < 8; k++) {
            int r = (w << 3) + k;
            int base = (int)rstart[r];
            int nr = (int)(rstart[r + 1] - rstart[r]);
            float a0 = 0.f, a1 = 0.f, a2 = 0.f, a3 = 0.f, dg = 0.f;
            int i = sub;
            for (; i + 12 < nr; i += 16) {       // 4 edges in flight per substream
                uint2 r0 = srt[base + i],     r1 = srt[base + i + 4];
                uint2 r2 = srt[base + i + 8], r3 = srt[base + i + 12];
                uint2 e0 = Ebf4[r0.x * 16u + q];
                uint2 e1 = Ebf4[r1.x * 16u + q];
                uint2 e2 = Ebf4[r2.x * 16u + q];
                uint2 e3 = Ebf4[r3.x * 16u + q];
                float w0 = __uint_as_float(r0.y), w1 = __uint_as_float(r1.y);
                float w2 = __uint_as_float(r2.y), w3 = __uint_as_float(r3.y);
                a0 += w0 * __uint_as_float(e0.x << 16);
                a1 += w0 * __uint_as_float(e0.x & 0xFFFF0000u);
                a2 += w0 * __uint_as_float(e0.y << 16);
                a3 += w0 * __uint_as_float(e0.y & 0xFFFF0000u);
                dg += w0;
                a0 += w1 * __uint_as_float(e1.x << 16);
                a1 += w1 * __uint_as_float(e1.x & 0xFFFF0000u);
                a2 += w1 * __uint_as_float(e1.y << 16);
                a3 += w1 * __uint_as_float(e1.y & 0xFFFF0000u);
                dg += w1;
                a0 += w2 * __uint_as_float(e2.x << 16);
                a1 += w2 * __uint_as_float(e2.x & 0xFFFF0000u);
                a2 += w2 * __uint_as_float(e2.y << 16);
                a3 += w2 * __uint_as_float(e2.y & 0xFFFF0000u);
                dg += w2;
                a0 += w3 * __uint_as_float(e3.x << 16);
                a1 += w3 * __uint_as_float(e3.x & 0xFFFF0000u);
                a2 += w3 * __uint_as_float(e3.y << 16);
                a3 += w3 * __uint_as_float(e3.y & 0xFFFF0000u);
                dg += w3;
            }
            for (; i < nr; i += 4) {
                uint2 r0 = srt[base + i];
                uint2 e0 = Ebf4[r0.x * 16u + q];
                float w0 = __uint_as_float(r0.y);
                a0 += w0 * __uint_as_float(e0.x << 16);
                a1 += w0 * __uint_as_float(e0.x & 0xFFFF0000u);
                a2 += w0 * __uint_as_float(e0.y << 16);
                a3 += w0 * __uint_as_float(e0.y & 0xFFFF0000u);
                dg += w0;
            }
            // combine 4 substreams (lanes differing in bits 4,5)
            a0 += __shfl_xor(a0, 16, 64);  a0 += __shfl_xor(a0, 32, 64);
            a1 += __shfl_xor(a1, 16, 64);  a1 += __shfl_xor(a1, 32, 64);
            a2 += __shfl_xor(a2, 16, 64);  a2 += __shfl_xor(a2, 32, 64);
            a3 += __shfl_xor(a3, 16, 64);  a3 += __shfl_xor(a3, 32, 64);
            dg += __shfl_xor(dg, 16, 64);  dg += __shfl_xor(dg, 32, 64);
            float inv = 1.0f / (3.0f * fmaxf(dg, 1.0f));
            if (sub == 0) {                      // exclusive owner: plain RMW
                float4 o = accT4[(r << 4) + q];
                accT4[(r << 4) + q] = make_float4(o.x + a0 * inv, o.y + a1 * inv,
                                                  o.z + a2 * inv, o.w + a3 * inv);
            }
        }
        __syncthreads();                         // srt/hist reuse next rel
    }

    int gbase2 = c * (CH_ROWS * EMBED_DIM);
    for (int k = t; k < CH_ROWS * EMBED_DIM; k += 512) {
        int gi = gbase2 + k;
        if (gi < N_ITEMS * EMBED_DIM) out[gi] = E[gi] + accT[k];
    }
}

// ============================ v5 fallback (R5 pipeline) ============================
#define NBS ((NKEY + 255) / 256)

__global__ void hist300_kernel(const int* __restrict__ rows, unsigned* __restrict__ cnt) {
    int stride = gridDim.x * blockDim.x;
    for (int i = blockIdx.x * blockDim.x + threadIdx.x; i < TOTAL_EDGES; i += stride) {
        unsigned r = (unsigned)i / (unsigned)N_EDGES;
        unsigned key = r * N_ITEMS + (unsigned)rows[i];
        atomicAdd(&cnt[key], 1u);
    }
}

__global__ void scan_blocksum(const unsigned* __restrict__ cnt, unsigned* __restrict__ bsum) {
    __shared__ unsigned s[256];
    int i = blockIdx.x * 256 + threadIdx.x;
    s[threadIdx.x] = (i < NKEY) ? cnt[i] : 0u;
    __syncthreads();
    for (int off = 128; off > 0; off >>= 1) {
        if (threadIdx.x < off) s[threadIdx.x] += s[threadIdx.x + off];
        __syncthreads();
    }
    if (threadIdx.x == 0) bsum[blockIdx.x] = s[0];
}

__global__ void scan_partials(unsigned* __restrict__ bsum, unsigned* __restrict__ starts) {
    const int IT = 5;
    int t = threadIdx.x;
    unsigned loc[IT];
    unsigned sum = 0;
    #pragma unroll
    for (int k = 0; k < IT; k++) {
        int idx = t * IT + k;
        loc[k] = (idx < NBS) ? bsum[idx] : 0u;
        sum += loc[k];
    }
    int lane = t & 63, wid = t >> 6;
    unsigned inc = sum;
    #pragma unroll
    for (int d = 1; d < 64; d <<= 1) {
        unsigned x = __shfl_up(inc, d, 64);
        if (lane >= d) inc += x;
    }
    __shared__ unsigned woff[4], woffEx[4];
    if (lane == 63) woff[wid] = inc;
    __syncthreads();
    if (t == 0) { unsigned run = 0; for (int k = 0; k < 4; k++) { woffEx[k] = run; run += woff[k]; } }
    __syncthreads();
    unsigned ex = inc - sum + woffEx[wid];
    #pragma unroll
    for (int k = 0; k < IT; k++) {
        int idx = t * IT + k;
        if (idx < NBS) { bsum[idx] = ex; ex += loc[k]; }
    }
    if (t == 0) starts[NKEY] = (unsigned)TOTAL_EDGES;
}

__global__ void scan_final(unsigned* key_arr,
                           const unsigned* __restrict__ bsum,
                           unsigned* __restrict__ cursor) {
    int i = blockIdx.x * 256 + threadIdx.x;
    unsigned v = (i < NKEY) ? key_arr[i] : 0u;
    int lane = threadIdx.x & 63, wid = threadIdx.x >> 6;
    unsigned inc = v;
    #pragma unroll
    for (int d = 1; d < 64; d <<= 1) {
        unsigned x = __shfl_up(inc, d, 64);
        if (lane >= d) inc += x;
    }
    __shared__ unsigned woff[4], woffEx[4];
    if (lane == 63) woff[wid] = inc;
    __syncthreads();
    if (threadIdx.x == 0) { unsigned run = 0; for (int k = 0; k < 4; k++) { woffEx[k] = run; run += woff[k]; } }
    __syncthreads();
    unsigned ex = inc - v + woffEx[wid] + bsum[blockIdx.x];
    if (i < NKEY) { key_arr[i] = ex; cursor[i] = ex; }
}

__global__ void binscatter2_kernel(const int* __restrict__ rows,
                                   const int* __restrict__ cols,
                                   const float* __restrict__ vals,
                                   unsigned* __restrict__ cursor,
                                   uint2* __restrict__ recs) {
    int stride = gridDim.x * blockDim.x;
    for (int i = blockIdx.x * blockDim.x + threadIdx.x; i < TOTAL_EDGES; i += stride) {
        unsigned r = (unsigned)i / (unsigned)N_EDGES;
        unsigned key = r * N_ITEMS + (unsigned)rows[i];
        unsigned pos = atomicAdd(&cursor[key], 1u);
        uint2 rec;
        rec.x = (unsigned)cols[i];
        rec.y = __float_as_uint(vals[i]);
        recs[pos] = rec;
    }
}

__launch_bounds__(192)
__global__ void gather_csr_f32_kernel(const float* __restrict__ E,
                                      const unsigned* __restrict__ starts,
                                      const uint2* __restrict__ recs,
                                      float* __restrict__ out) {
    __shared__ float part[N_REL * EMBED_DIM];
    int row = blockIdx.x;
    int w = threadIdx.x >> 6;
    int d = threadIdx.x & 63;
    unsigned key = (unsigned)w * N_ITEMS + (unsigned)row;
    unsigned s = starts[key];
    int n = (int)(starts[key + 1] - s);
    const uint2* __restrict__ p = recs + s;
    float acc = 0.0f, deg = 0.0f;
    int j = 0;
    for (; j + 8 <= n; j += 8) {
        uint2 a[8];
        #pragma unroll
        for (int k = 0; k < 8; k++) a[k] = p[j + k];
        float e[8];
        #pragma unroll
        for (int k = 0; k < 8; k++) e[k] = E[a[k].x * EMBED_DIM + d];
        #pragma unroll
        for (int k = 0; k < 8; k++) {
            float wv = __uint_as_float(a[k].y);
            acc += wv * e[k];
            deg += wv;
        }
    }
    for (; j < n; j++) {
        uint2 a = p[j];
        float wv = __uint_as_float(a.y);
        acc += wv * E[a.x * EMBED_DIM + d];
        deg += wv;
    }
    part[w * EMBED_DIM + d] = acc / (3.0f * fmaxf(deg, 1.0f));
    __syncthreads();
    if (threadIdx.x < EMBED_DIM) {
        int gi = row * EMBED_DIM + threadIdx.x;
        out[gi] = E[gi] + part[threadIdx.x]
                        + part[EMBED_DIM + threadIdx.x]
                        + part[2 * EMBED_DIM + threadIdx.x];
    }
}

// ============================ R1 fallback ============================
__global__ void deg_kernel(const int* __restrict__ rows,
                           const float* __restrict__ vals,
                           float* __restrict__ deg) {
    long long i = (long long)blockIdx.x * blockDim.x + threadIdx.x;
    if (i >= TOTAL_EDGES) return;
    int r = (int)(i / N_EDGES);
    int row = rows[i];
    atomicAdd(&deg[(long long)r * N_ITEMS + row], vals[i]);
}

__global__ void inv_kernel(float* __restrict__ deg) {
    int i = blockIdx.x * blockDim.x + threadIdx.x;
    if (i >= N_REL * N_ITEMS) return;
    float d = deg[i];
    d = fmaxf(d, 1.0f);
    deg[i] = 1.0f / (3.0f * d);
}

__global__ void scatter_kernel(const float* __restrict__ E,
                               const int* __restrict__ rows,
                               const int* __restrict__ cols,
                               const float* __restrict__ vals,
                               const float* __restrict__ inv,
                               float* __restrict__ out) {
    long long t = (long long)blockIdx.x * blockDim.x + threadIdx.x;
    long long edge = t >> 6;
    int d = (int)(t & 63);
    if (edge >= TOTAL_EDGES) return;
    int r = (int)(edge / N_EDGES);
    int row = rows[edge];
    int col = cols[edge];
    float w = vals[edge] * inv[r * N_ITEMS + row];
    float msg = w * E[(long long)col * EMBED_DIM + d];
    atomicAdd(&out[(long long)row * EMBED_DIM + d], msg);
}

// ============================ launcher ============================
extern "C" void kernel_launch(void* const* d_in, const int* in_sizes, int n_in,
                              void* d_out, int out_size, void* d_ws, size_t ws_size,
                              hipStream_t stream) {
    const float* E    = (const float*)d_in[0];
    const int*   rows = (const int*)d_in[1];
    const int*   cols = (const int*)d_in[2];
    const float* vals = (const float*)d_in[3];
    float* out = (float*)d_out;

    // v15 workspace: [GC 32KB: gcursorF@0, cursorC@20480] | coarse (1 or 3 rel
    // regions) | fine recs | Ebf
    const size_t GCB      = 32768;
    const size_t COARSE1  = (size_t)NCB * CBCAP * sizeof(uint2);    // 27.85 MB / rel
    const size_t FINE_B   = (size_t)NBKT * BCAP * sizeof(uint2);    // 88.83 MB
    const size_t EBF_B    = (size_t)N_ITEMS * EMBED_DIM * 2;        // 12.8 MB
    size_t need15 = GCB + 3 * COARSE1 + FINE_B + EBF_B;             // ~185.2 MB
    size_t need11 = GCB + COARSE1 + FINE_B + EBF_B;                 // ~129.5 MB (proven fits)

    // v5 fallback sizes
    const size_t REGA = 1204224;                                    // >= (NKEY+1)*4
    const size_t REGC = 8192;
    const size_t RECB = (size_t)TOTAL_EDGES * sizeof(uint2);        // 76.8 MB
    size_t need5 = 2 * REGA + REGC + RECB;

    int initGrid = (N_ITEMS * 16 + 255) / 256;

    if (ws_size >= need15) {
        // fused 3-rel partition: 2 launches
        unsigned* gcursorF = (unsigned*)d_ws;
        unsigned* cursorC  = (unsigned*)((char*)d_ws + 20480);
        uint2*    coarse   = (uint2*)((char*)d_ws + GCB);
        uint2*    recs     = (uint2*)((char*)d_ws + GCB + 3 * COARSE1);
        unsigned short* Ebf = (unsigned short*)((char*)d_ws + GCB + 3 * COARSE1 + FINE_B);

        init15_kernel<<<initGrid, 256, 0, stream>>>(E, Ebf, gcursorF, cursorC);
        partA4_kernel<<<N_REL * NTILEP, 256, 0, stream>>>(
            rows, cols, vals, cursorC, coarse, 0, (unsigned)(NCB * CBCAP));
        partB4_kernel<<<N_REL * NCB * SEGSB, 256, 0, stream>>>(
            cursorC, coarse, gcursorF, recs, 0, (unsigned)(NCB * CBCAP));
        gather_sort_kernel<<<NCHUNK, 512, 0, stream>>>((const uint2*)Ebf, E, gcursorF, recs, out);
    } else if (ws_size >= need11) {
        // per-rel loop, coarse buffer reused (proven layout)
        unsigned* gcursorF = (unsigned*)d_ws;
        unsigned* cursorC  = (unsigned*)((char*)d_ws + 20480);
        uint2*    coarse   = (uint2*)((char*)d_ws + GCB);
        uint2*    recs     = (uint2*)((char*)d_ws + GCB + COARSE1);
        unsigned short* Ebf = (unsigned short*)((char*)d_ws + GCB + COARSE1 + FINE_B);

        init15_kernel<<<initGrid, 256, 0, stream>>>(E, Ebf, gcursorF, cursorC);
        for (int r = 0; r < N_REL; r++) {
            partA4_kernel<<<NTILEP, 256, 0, stream>>>(
                rows, cols, vals, cursorC, coarse, r, 0u);
            partB4_kernel<<<NCB * SEGSB, 256, 0, stream>>>(
                cursorC, coarse, gcursorF, recs, r, 0u);
        }
        gather_sort_kernel<<<NCHUNK, 512, 0, stream>>>((const uint2*)Ebf, E, gcursorF, recs, out);
    } else if (ws_size >= need5) {
        unsigned* keyA   = (unsigned*)d_ws;
        unsigned* cursor = (unsigned*)((char*)d_ws + REGA);
        unsigned* bsum   = (unsigned*)((char*)d_ws + 2 * REGA);
        uint2*    recs   = (uint2*)((char*)d_ws + 2 * REGA + REGC);

        hipMemsetAsync(keyA, 0, NKEY * sizeof(unsigned), stream);
        hist300_kernel<<<1536, 256, 0, stream>>>(rows, keyA);
        scan_blocksum<<<NBS, 256, 0, stream>>>(keyA, bsum);
        scan_partials<<<1, 256, 0, stream>>>(bsum, keyA);
        scan_final<<<NBS, 256, 0, stream>>>(keyA, bsum, cursor);
        binscatter2_kernel<<<2048, 256, 0, stream>>>(rows, cols, vals, cursor, recs);
        gather_csr_f32_kernel<<<N_ITEMS, 192, 0, stream>>>(E, keyA, recs, out);
    } else {
        float* deg = (float*)d_ws;
        hipMemsetAsync(deg, 0, (size_t)N_REL * N_ITEMS * sizeof(float), stream);
        {
            long long total = TOTAL_EDGES;
            int block = 256;
            long long grid = (total + block - 1) / block;
            deg_kernel<<<(unsigned)grid, block, 0, stream>>>(rows, vals, deg);
        }
        {
            int total = N_REL * N_ITEMS;
            int block = 256;
            int grid = (total + block - 1) / block;
            inv_kernel<<<grid, block, 0, stream>>>(deg);
        }
        hipMemcpyAsync(out, E, (size_t)N_ITEMS * EMBED_DIM * sizeof(float),
                       hipMemcpyDeviceToDevice, stream);
        {
            long long threads = (long long)TOTAL_EDGES * 64;
            int block = 256;
            long long grid = (threads + block - 1) / block;
            scatter_kernel<<<(unsigned)grid, block, 0, stream>>>(E, rows, cols, vals, deg, out);
        }
    }
}

// Round 8
// 370.622 us; speedup vs baseline: 1.9486x; 1.1907x over previous
//
#include <hip/hip_runtime.h>

// Problem constants (from reference)
#define N_ITEMS     100000
#define EMBED_DIM   64
#define N_REL       3
#define N_EDGES     3200000
#define TOTAL_EDGES (N_REL * N_EDGES)   // 9,600,000 (fits int)
#define NKEY        (N_REL * N_ITEMS)   // 300,000 (v5 fallback)

// == v16: best-of-breed — v13 partition (202us) + v12 gather (165us) + v15 init ==
// Fine buckets (gather granularity): 64-row chunk x rel, capacity slots.
#define LOG_CH   6
#define CH_ROWS  64
#define NCHUNK   1563                       // ceil(100000/64)
#define NBKT     (NCHUNK * N_REL)           // 4689
#define BCAP     2368                       // mean 2048 + ~7 sigma (proven R2-R7)
// Coarse buckets: 4096-row chunks; cursors RELATIVE to each rel's region.
#define LOG_CB   12
#define NCB      25                         // ceil(100000/4096)
#define TILEP    4096                       // staged tile (32KB+4KB LDS) — v13-proven
#define NTILEP   ((N_EDGES + TILEP - 1) / TILEP)   // 782 tiles per rel
#define SEGSB    34
#define CBCAP    (SEGSB * TILEP)            // 139264 = mean 131072 + slack (proven)

// ---- v16.1: fused init (cursors) + vectorized E -> bf16 (v15-proven) ----
__global__ void init16_kernel(const float* __restrict__ E,
                              unsigned short* __restrict__ Ebf,
                              unsigned* __restrict__ gcursorF,
                              unsigned* __restrict__ cursorC) {
    int i = blockIdx.x * 256 + threadIdx.x;
    if (i < NBKT) gcursorF[i] = (unsigned)i * (unsigned)BCAP;
    if (i < N_REL * NCB) cursorC[i] = (unsigned)(i % NCB) * (unsigned)CBCAP;
    if (i < N_ITEMS * 16) {                 // 4 floats -> 4 bf16 per thread
        float4 f = ((const float4*)E)[i];
        unsigned u0 = __float_as_uint(f.x), u1 = __float_as_uint(f.y);
        unsigned u2 = __float_as_uint(f.z), u3 = __float_as_uint(f.w);
        ushort4 o;
        o.x = (unsigned short)((u0 + 0x7FFFu + ((u0 >> 16) & 1u)) >> 16);  // RNE
        o.y = (unsigned short)((u1 + 0x7FFFu + ((u1 >> 16) & 1u)) >> 16);
        o.z = (unsigned short)((u2 + 0x7FFFu + ((u2 >> 16) & 1u)) >> 16);
        o.w = (unsigned short)((u3 + 0x7FFFu + ((u3 >> 16) & 1u)) >> 16);
        ((ushort4*)Ebf)[i] = o;
    }
}

// ---- v16.2 pass A (v13-proven): 8/thread reg-staged partition, 25 coarse buckets ----
// coarse rec: x = col(17b) | lrow12 << 17 ; y = val bits.
__launch_bounds__(512, 8)
__global__ void partA3_kernel(const int* __restrict__ rows,
                              const int* __restrict__ cols,
                              const float* __restrict__ vals,
                              unsigned* __restrict__ cursorC,
                              uint2* __restrict__ coarse,
                              int rel0, unsigned relStrideU2) {
    __shared__ uint2 stag[TILEP];              // 32 KB
    __shared__ unsigned char bkt[TILEP];       // 4 KB
    __shared__ unsigned hist[NCB], lstart[NCB], gbase[NCB], lcur[NCB];
    int rel = rel0 + blockIdx.x / NTILEP;
    int base = (blockIdx.x % NTILEP) * TILEP;
    int cnt = N_EDGES - base; if (cnt > TILEP) cnt = TILEP;
    int t = threadIdx.x;
    const int go = rel * N_EDGES + base;
    uint2* __restrict__ coarseRel = coarse + (size_t)(rel - rel0) * relStrideU2;

    // stage 8 edges/thread into registers (single global read of the tile)
    unsigned rrow[8], rcol[8], rval[8];
    #pragma unroll
    for (int k = 0; k < 8; k++) {
        int i = t + (k << 9);
        if (i < cnt) {
            rrow[k] = (unsigned)rows[go + i];
            rcol[k] = (unsigned)cols[go + i];
            rval[k] = __float_as_uint(vals[go + i]);
        } else rrow[k] = 0xFFFFFFFFu;
    }
    if (t < NCB) hist[t] = 0u;
    __syncthreads();
    #pragma unroll
    for (int k = 0; k < 8; k++)
        if (rrow[k] != 0xFFFFFFFFu) atomicAdd(&hist[rrow[k] >> LOG_CB], 1u);
    __syncthreads();
    if (t < 32) {                              // wave-parallel scan of 25 bins
        unsigned v = (t < NCB) ? hist[t] : 0u;
        unsigned inc = v;
        #pragma unroll
        for (int d = 1; d < 32; d <<= 1) {
            unsigned x = __shfl_up(inc, d, 32);
            if (t >= d) inc += x;
        }
        if (t < NCB) {
            unsigned ex = inc - v;
            lstart[t] = ex; lcur[t] = ex;
            if (v) gbase[t] = atomicAdd(&cursorC[rel * NCB + t], v);
        }
    }
    __syncthreads();
    #pragma unroll
    for (int k = 0; k < 8; k++)
        if (rrow[k] != 0xFFFFFFFFu) {
            unsigned row = rrow[k];
            unsigned cb = row >> LOG_CB;
            unsigned dst = atomicAdd(&lcur[cb], 1u);
            stag[dst] = make_uint2(rcol[k] | ((row & 4095u) << 17), rval[k]);
            bkt[dst] = (unsigned char)cb;
        }
    __syncthreads();
    // flush: consecutive staged slots of a bucket -> consecutive global slots
    for (int i = t; i < cnt; i += 512) {
        unsigned bb = bkt[i];
        unsigned dst = gbase[bb] + ((unsigned)i - lstart[bb]);
        if (dst < (bb + 1u) * (unsigned)CBCAP) coarseRel[dst] = stag[i];
    }
}

// ---- v16.3 pass B (v13-proven): 8/thread reg-staged refine into 64 fine buckets ----
// fine rec: x = col(17b) | lrow6 << 17 ; y = val bits.
__launch_bounds__(512, 8)
__global__ void partB3_kernel(const unsigned* __restrict__ cursorC,
                              const uint2* __restrict__ coarse,
                              unsigned* __restrict__ gcursorF,
                              uint2* __restrict__ recs,
                              int rel0, unsigned relStrideU2) {
    __shared__ uint2 stag[TILEP];              // 32 KB
    __shared__ unsigned char bkt[TILEP];       // 4 KB
    __shared__ unsigned hist[64], lstart[64], gbase[64], lcur[64];
    int rel = rel0 + blockIdx.x / (NCB * SEGSB);
    int rem = blockIdx.x % (NCB * SEGSB);
    int cb = rem / SEGSB, seg = rem % SEGSB;
    unsigned cntA = cursorC[rel * NCB + cb] - (unsigned)cb * (unsigned)CBCAP;
    if (cntA > (unsigned)CBCAP) cntA = (unsigned)CBCAP;
    int off = seg * TILEP;
    int cnt = (int)cntA - off;
    if (cnt <= 0) return;                      // block-uniform: no divergent barrier
    if (cnt > TILEP) cnt = TILEP;
    const uint2* __restrict__ src = coarse + (size_t)(rel - rel0) * relStrideU2
                                  + (unsigned)cb * (unsigned)CBCAP + off;
    int t = threadIdx.x;

    uint2 rc[8];
    #pragma unroll
    for (int k = 0; k < 8; k++) {
        int i = t + (k << 9);
        rc[k] = (i < cnt) ? src[i] : make_uint2(0xFFFFFFFFu, 0u);
    }
    if (t < 64) hist[t] = 0u;
    __syncthreads();
    #pragma unroll
    for (int k = 0; k < 8; k++)
        if (rc[k].x != 0xFFFFFFFFu) atomicAdd(&hist[(rc[k].x >> 23) & 63u], 1u);
    __syncthreads();
    if (t < 64) {                              // wave0: full shfl scan of 64 bins
        unsigned v = hist[t];
        unsigned inc = v;
        #pragma unroll
        for (int d = 1; d < 64; d <<= 1) {
            unsigned x = __shfl_up(inc, d, 64);
            if (t >= d) inc += x;
        }
        unsigned ex = inc - v;
        lstart[t] = ex; lcur[t] = ex;
        if (v) gbase[t] = atomicAdd(&gcursorF[(((unsigned)cb << 6) + t) * 3u + rel], v);
    }
    __syncthreads();
    #pragma unroll
    for (int k = 0; k < 8; k++)
        if (rc[k].x != 0xFFFFFFFFu) {
            unsigned j = (rc[k].x >> 23) & 63u;
            unsigned dst = atomicAdd(&lcur[j], 1u);
            stag[dst] = make_uint2(rc[k].x & 0x7FFFFFu, rc[k].y);
            bkt[dst] = (unsigned char)j;
        }
    __syncthreads();
    for (int i = t; i < cnt; i += 512) {
        unsigned j = bkt[i];
        unsigned bf = (((unsigned)cb << 6) + j) * 3u + rel;
        unsigned dst = gbase[j] + ((unsigned)i - lstart[j]);
        if (dst < (bf + 1u) * (unsigned)BCAP) recs[dst] = stag[i];
    }
}

// ---- v16.4: fused count-sort + gather — BYTE-IDENTICAL to v12/v15 (165 µs) ----
__launch_bounds__(512, 8)
__global__ void gather_sort_kernel(const uint2* __restrict__ Ebf4,   // ushort4 rows viewed as uint2
                                   const float* __restrict__ E,
                                   const unsigned* __restrict__ gcursorF,
                                   const uint2* __restrict__ recs,
                                   float* __restrict__ out) {
    __shared__ uint2  srt[BCAP];                 // 18.5 KB sorted records
    __shared__ float4 accT4[CH_ROWS * 16];       // 16 KB fp32 accumulation tile
    __shared__ unsigned hist[CH_ROWS], cur[CH_ROWS], rstart[CH_ROWS + 1];
    int c = blockIdx.x;
    int t = threadIdx.x;
    int w = t >> 6;            // wave 0..7 -> owns rows 8w..8w+7
    int lane = t & 63;
    int sub = lane >> 4;       // edge substream 0..3
    int q = lane & 15;         // dim quad (4q..4q+3)

    float* accT = (float*)accT4;
    for (int k = t; k < CH_ROWS * EMBED_DIM; k += 512) accT[k] = 0.f;

    for (int rel = 0; rel < N_REL; rel++) {
        unsigned b = (unsigned)(c * N_REL + rel);
        unsigned s0 = b * (unsigned)BCAP;
        int n = (int)(gcursorF[b] - s0);
        if (n > BCAP) n = BCAP;
        const uint2* __restrict__ pg = recs + s0;

        // register-stage this bucket's records (single global read)
        uint2 rc[5];
        #pragma unroll
        for (int k = 0; k < 5; k++) {
            int i = t + (k << 9);
            rc[k] = (i < n) ? pg[i] : make_uint2(0u, 0u);
        }
        if (t < CH_ROWS) hist[t] = 0u;
        __syncthreads();
        #pragma unroll
        for (int k = 0; k < 5; k++) {
            int i = t + (k << 9);
            if (i < n) atomicAdd(&hist[rc[k].x >> 17], 1u);
        }
        __syncthreads();
        if (t < 64) {                            // wave 0: exclusive scan of 64 bins
            unsigned v = hist[t];
            unsigned inc = v;
            #pragma unroll
            for (int d = 1; d < 64; d <<= 1) {
                unsigned x = __shfl_up(inc, d, 64);
                if (lane >= d) inc += x;
            }
            rstart[t] = inc - v;
            cur[t] = inc - v;
            if (t == 63) rstart[64] = inc;
        }
        __syncthreads();
        #pragma unroll
        for (int k = 0; k < 5; k++) {            // sort-scatter from registers
            int i = t + (k << 9);
            if (i < n) {
                unsigned pos = atomicAdd(&cur[rc[k].x >> 17], 1u);
                srt[pos] = make_uint2(rc[k].x & 0x1FFFFu, rc[k].y);
            }
        }
        __syncthreads();

        // ---- per-row register gather (R0-proven 16-lane x 4-substream, 4-deep) ----
        for (int k = 0; k < 8; k++) {
            int r = (w << 3) + k;
            int base = (int)rstart[r];
            int nr = (int)(rstart[r + 1] - rstart[r]);
            float a0 = 0.f, a1 = 0.f, a2 = 0.f, a3 = 0.f, dg = 0.f;
            int i = sub;
            for (; i + 12 < nr; i += 16) {       // 4 edges in flight per substream
                uint2 r0 = srt[base + i],     r1 = srt[base + i + 4];
                uint2 r2 = srt[base + i + 8], r3 = srt[base + i + 12];
                uint2 e0 = Ebf4[r0.x * 16u + q];
                uint2 e1 = Ebf4[r1.x * 16u + q];
                uint2 e2 = Ebf4[r2.x * 16u + q];
                uint2 e3 = Ebf4[r3.x * 16u + q];
                float w0 = __uint_as_float(r0.y), w1 = __uint_as_float(r1.y);
                float w2 = __uint_as_float(r2.y), w3 = __uint_as_float(r3.y);
                a0 += w0 * __uint_as_float(e0.x << 16);
                a1 += w0 * __uint_as_float(e0.x & 0xFFFF0000u);
                a2 += w0 * __uint_as_float(e0.y << 16);
                a3 += w0 * __uint_as_float(e0.y & 0xFFFF0000u);
                dg += w0;
                a0 += w1 * __uint_as_float(e1.x << 16);
                a1 += w1 * __uint_as_float(e1.x & 0xFFFF0000u);
                a2 += w1 * __uint_as_float(e1.y << 16);
                a3 += w1 * __uint_as_float(e1.y & 0xFFFF0000u);
                dg += w1;
                a0 += w2 * __uint_as_float(e2.x << 16);
                a1 += w2 * __uint_as_float(e2.x & 0xFFFF0000u);
                a2 += w2 * __uint_as_float(e2.y << 16);
                a3 += w2 * __uint_as_float(e2.y & 0xFFFF0000u);
                dg += w2;
                a0 += w3 * __uint_as_float(e3.x << 16);
                a1 += w3 * __uint_as_float(e3.x & 0xFFFF0000u);
                a2 += w3 * __uint_as_float(e3.y << 16);
                a3 += w3 * __uint_as_float(e3.y & 0xFFFF0000u);
                dg += w3;
            }
            for (; i < nr; i += 4) {
                uint2 r0 = srt[base + i];
                uint2 e0 = Ebf4[r0.x * 16u + q];
                float w0 = __uint_as_float(r0.y);
                a0 += w0 * __uint_as_float(e0.x << 16);
                a1 += w0 * __uint_as_float(e0.x & 0xFFFF0000u);
                a2 += w0 * __uint_as_float(e0.y << 16);
                a3 += w0 * __uint_as_float(e0.y & 0xFFFF0000u);
                dg += w0;
            }
            // combine 4 substreams (lanes differing in bits 4,5)
            a0 += __shfl_xor(a0, 16, 64);  a0 += __shfl_xor(a0, 32, 64);
            a1 += __shfl_xor(a1, 16, 64);  a1 += __shfl_xor(a1, 32, 64);
            a2 += __shfl_xor(a2, 16, 64);  a2 += __shfl_xor(a2, 32, 64);
            a3 += __shfl_xor(a3, 16, 64);  a3 += __shfl_xor(a3, 32, 64);
            dg += __shfl_xor(dg, 16, 64);  dg += __shfl_xor(dg, 32, 64);
            float inv = 1.0f / (3.0f * fmaxf(dg, 1.0f));
            if (sub == 0) {                      // exclusive owner: plain RMW
                float4 o = accT4[(r << 4) + q];
                accT4[(r << 4) + q] = make_float4(o.x + a0 * inv, o.y + a1 * inv,
                                                  o.z + a2 * inv, o.w + a3 * inv);
            }
        }
        __syncthreads();                         // srt/hist reuse next rel
    }

    int gbase2 = c * (CH_ROWS * EMBED_DIM);
    for (int k = t; k < CH_ROWS * EMBED_DIM; k += 512) {
        int gi = gbase2 + k;
        if (gi < N_ITEMS * EMBED_DIM) out[gi] = E[gi] + accT[k];
    }
}

// ============================ v5 fallback (R5 pipeline) ============================
#define NBS ((NKEY + 255) / 256)

__global__ void hist300_kernel(const int* __restrict__ rows, unsigned* __restrict__ cnt) {
    int stride = gridDim.x * blockDim.x;
    for (int i = blockIdx.x * blockDim.x + threadIdx.x; i < TOTAL_EDGES; i += stride) {
        unsigned r = (unsigned)i / (unsigned)N_EDGES;
        unsigned key = r * N_ITEMS + (unsigned)rows[i];
        atomicAdd(&cnt[key], 1u);
    }
}

__global__ void scan_blocksum(const unsigned* __restrict__ cnt, unsigned* __restrict__ bsum) {
    __shared__ unsigned s[256];
    int i = blockIdx.x * 256 + threadIdx.x;
    s[threadIdx.x] = (i < NKEY) ? cnt[i] : 0u;
    __syncthreads();
    for (int off = 128; off > 0; off >>= 1) {
        if (threadIdx.x < off) s[threadIdx.x] += s[threadIdx.x + off];
        __syncthreads();
    }
    if (threadIdx.x == 0) bsum[blockIdx.x] = s[0];
}

__global__ void scan_partials(unsigned* __restrict__ bsum, unsigned* __restrict__ starts) {
    const int IT = 5;
    int t = threadIdx.x;
    unsigned loc[IT];
    unsigned sum = 0;
    #pragma unroll
    for (int k = 0; k < IT; k++) {
        int idx = t * IT + k;
        loc[k] = (idx < NBS) ? bsum[idx] : 0u;
        sum += loc[k];
    }
    int lane = t & 63, wid = t >> 6;
    unsigned inc = sum;
    #pragma unroll
    for (int d = 1; d < 64; d <<= 1) {
        unsigned x = __shfl_up(inc, d, 64);
        if (lane >= d) inc += x;
    }
    __shared__ unsigned woff[4], woffEx[4];
    if (lane == 63) woff[wid] = inc;
    __syncthreads();
    if (t == 0) { unsigned run = 0; for (int k = 0; k < 4; k++) { woffEx[k] = run; run += woff[k]; } }
    __syncthreads();
    unsigned ex = inc - sum + woffEx[wid];
    #pragma unroll
    for (int k = 0; k < IT; k++) {
        int idx = t * IT + k;
        if (idx < NBS) { bsum[idx] = ex; ex += loc[k]; }
    }
    if (t == 0) starts[NKEY] = (unsigned)TOTAL_EDGES;
}

__global__ void scan_final(unsigned* key_arr,
                           const unsigned* __restrict__ bsum,
                           unsigned* __restrict__ cursor) {
    int i = blockIdx.x * 256 + threadIdx.x;
    unsigned v = (i < NKEY) ? key_arr[i] : 0u;
    int lane = threadIdx.x & 63, wid = threadIdx.x >> 6;
    unsigned inc = v;
    #pragma unroll
    for (int d = 1; d < 64; d <<= 1) {
        unsigned x = __shfl_up(inc, d, 64);
        if (lane >= d) inc += x;
    }
    __shared__ unsigned woff[4], woffEx[4];
    if (lane == 63) woff[wid] = inc;
    __syncthreads();
    if (threadIdx.x == 0) { unsigned run = 0; for (int k = 0; k < 4; k++) { woffEx[k] = run; run += woff[k]; } }
    __syncthreads();
    unsigned ex = inc - v + woffEx[wid] + bsum[blockIdx.x];
    if (i < NKEY) { key_arr[i] = ex; cursor[i] = ex; }
}

__global__ void binscatter2_kernel(const int* __restrict__ rows,
                                   const int* __restrict__ cols,
                                   const float* __restrict__ vals,
                                   unsigned* __restrict__ cursor,
                                   uint2* __restrict__ recs) {
    int stride = gridDim.x * blockDim.x;
    for (int i = blockIdx.x * blockDim.x + threadIdx.x; i < TOTAL_EDGES; i += stride) {
        unsigned r = (unsigned)i / (unsigned)N_EDGES;
        unsigned key = r * N_ITEMS + (unsigned)rows[i];
        unsigned pos = atomicAdd(&cursor[key], 1u);
        uint2 rec;
        rec.x = (unsigned)cols[i];
        rec.y = __float_as_uint(vals[i]);
        recs[pos] = rec;
    }
}

__launch_bounds__(192)
__global__ void gather_csr_f32_kernel(const float* __restrict__ E,
                                      const unsigned* __restrict__ starts,
                                      const uint2* __restrict__ recs,
                                      float* __restrict__ out) {
    __shared__ float part[N_REL * EMBED_DIM];
    int row = blockIdx.x;
    int w = threadIdx.x >> 6;
    int d = threadIdx.x & 63;
    unsigned key = (unsigned)w * N_ITEMS + (unsigned)row;
    unsigned s = starts[key];
    int n = (int)(starts[key + 1] - s);
    const uint2* __restrict__ p = recs + s;
    float acc = 0.0f, deg = 0.0f;
    int j = 0;
    for (; j + 8 <= n; j += 8) {
        uint2 a[8];
        #pragma unroll
        for (int k = 0; k < 8; k++) a[k] = p[j + k];
        float e[8];
        #pragma unroll
        for (int k = 0; k < 8; k++) e[k] = E[a[k].x * EMBED_DIM + d];
        #pragma unroll
        for (int k = 0; k < 8; k++) {
            float wv = __uint_as_float(a[k].y);
            acc += wv * e[k];
            deg += wv;
        }
    }
    for (; j < n; j++) {
        uint2 a = p[j];
        float wv = __uint_as_float(a.y);
        acc += wv * E[a.x * EMBED_DIM + d];
        deg += wv;
    }
    part[w * EMBED_DIM + d] = acc / (3.0f * fmaxf(deg, 1.0f));
    __syncthreads();
    if (threadIdx.x < EMBED_DIM) {
        int gi = row * EMBED_DIM + threadIdx.x;
        out[gi] = E[gi] + part[threadIdx.x]
                        + part[EMBED_DIM + threadIdx.x]
                        + part[2 * EMBED_DIM + threadIdx.x];
    }
}

// ============================ R1 fallback ============================
__global__ void deg_kernel(const int* __restrict__ rows,
                           const float* __restrict__ vals,
                           float* __restrict__ deg) {
    long long i = (long long)blockIdx.x * blockDim.x + threadIdx.x;
    if (i >= TOTAL_EDGES) return;
    int r = (int)(i / N_EDGES);
    int row = rows[i];
    atomicAdd(&deg[(long long)r * N_ITEMS + row], vals[i]);
}

__global__ void inv_kernel(float* __restrict__ deg) {
    int i = blockIdx.x * blockDim.x + threadIdx.x;
    if (i >= N_REL * N_ITEMS) return;
    float d = deg[i];
    d = fmaxf(d, 1.0f);
    deg[i] = 1.0f / (3.0f * d);
}

__global__ void scatter_kernel(const float* __restrict__ E,
                               const int* __restrict__ rows,
                               const int* __restrict__ cols,
                               const float* __restrict__ vals,
                               const float* __restrict__ inv,
                               float* __restrict__ out) {
    long long t = (long long)blockIdx.x * blockDim.x + threadIdx.x;
    long long edge = t >> 6;
    int d = (int)(t & 63);
    if (edge >= TOTAL_EDGES) return;
    int r = (int)(edge / N_EDGES);
    int row = rows[edge];
    int col = cols[edge];
    float w = vals[edge] * inv[r * N_ITEMS + row];
    float msg = w * E[(long long)col * EMBED_DIM + d];
    atomicAdd(&out[(long long)row * EMBED_DIM + d], msg);
}

// ============================ launcher ============================
extern "C" void kernel_launch(void* const* d_in, const int* in_sizes, int n_in,
                              void* d_out, int out_size, void* d_ws, size_t ws_size,
                              hipStream_t stream) {
    const float* E    = (const float*)d_in[0];
    const int*   rows = (const int*)d_in[1];
    const int*   cols = (const int*)d_in[2];
    const float* vals = (const float*)d_in[3];
    float* out = (float*)d_out;

    // v16 workspace: [GC 32KB: gcursorF@0, cursorC@20480] | coarse (1 or 3 rel
    // regions) | fine recs | Ebf
    const size_t GCB      = 32768;
    const size_t COARSE1  = (size_t)NCB * CBCAP * sizeof(uint2);    // 27.85 MB / rel
    const size_t FINE_B   = (size_t)NBKT * BCAP * sizeof(uint2);    // 88.83 MB
    const size_t EBF_B    = (size_t)N_ITEMS * EMBED_DIM * 2;        // 12.8 MB
    size_t need16 = GCB + 3 * COARSE1 + FINE_B + EBF_B;             // ~185.2 MB (proven fits R4-R7)
    size_t need11 = GCB + COARSE1 + FINE_B + EBF_B;                 // ~129.5 MB (proven fits)

    // v5 fallback sizes
    const size_t REGA = 1204224;                                    // >= (NKEY+1)*4
    const size_t REGC = 8192;
    const size_t RECB = (size_t)TOTAL_EDGES * sizeof(uint2);        // 76.8 MB
    size_t need5 = 2 * REGA + REGC + RECB;

    int initGrid = (N_ITEMS * 16 + 255) / 256;

    if (ws_size >= need16) {
        // fused 3-rel partition: 2 launches
        unsigned* gcursorF = (unsigned*)d_ws;
        unsigned* cursorC  = (unsigned*)((char*)d_ws + 20480);
        uint2*    coarse   = (uint2*)((char*)d_ws + GCB);
        uint2*    recs     = (uint2*)((char*)d_ws + GCB + 3 * COARSE1);
        unsigned short* Ebf = (unsigned short*)((char*)d_ws + GCB + 3 * COARSE1 + FINE_B);

        init16_kernel<<<initGrid, 256, 0, stream>>>(E, Ebf, gcursorF, cursorC);
        partA3_kernel<<<N_REL * NTILEP, 512, 0, stream>>>(
            rows, cols, vals, cursorC, coarse, 0, (unsigned)(NCB * CBCAP));
        partB3_kernel<<<N_REL * NCB * SEGSB, 512, 0, stream>>>(
            cursorC, coarse, gcursorF, recs, 0, (unsigned)(NCB * CBCAP));
        gather_sort_kernel<<<NCHUNK, 512, 0, stream>>>((const uint2*)Ebf, E, gcursorF, recs, out);
    } else if (ws_size >= need11) {
        // per-rel loop, coarse buffer reused (proven layout)
        unsigned* gcursorF = (unsigned*)d_ws;
        unsigned* cursorC  = (unsigned*)((char*)d_ws + 20480);
        uint2*    coarse   = (uint2*)((char*)d_ws + GCB);
        uint2*    recs     = (uint2*)((char*)d_ws + GCB + COARSE1);
        unsigned short* Ebf = (unsigned short*)((char*)d_ws + GCB + COARSE1 + FINE_B);

        init16_kernel<<<initGrid, 256, 0, stream>>>(E, Ebf, gcursorF, cursorC);
        for (int r = 0; r < N_REL; r++) {
            partA3_kernel<<<NTILEP, 512, 0, stream>>>(
                rows, cols, vals, cursorC, coarse, r, 0u);
            partB3_kernel<<<NCB * SEGSB, 512, 0, stream>>>(
                cursorC, coarse, gcursorF, recs, r, 0u);
        }
        gather_sort_kernel<<<NCHUNK, 512, 0, stream>>>((const uint2*)Ebf, E, gcursorF, recs, out);
    } else if (ws_size >= need5) {
        unsigned* keyA   = (unsigned*)d_ws;
        unsigned* cursor = (unsigned*)((char*)d_ws + REGA);
        unsigned* bsum   = (unsigned*)((char*)d_ws + 2 * REGA);
        uint2*    recs   = (uint2*)((char*)d_ws + 2 * REGA + REGC);

        hipMemsetAsync(keyA, 0, NKEY * sizeof(unsigned), stream);
        hist300_kernel<<<1536, 256, 0, stream>>>(rows, keyA);
        scan_blocksum<<<NBS, 256, 0, stream>>>(keyA, bsum);
        scan_partials<<<1, 256, 0, stream>>>(bsum, keyA);
        scan_final<<<NBS, 256, 0, stream>>>(keyA, bsum, cursor);
        binscatter2_kernel<<<2048, 256, 0, stream>>>(rows, cols, vals, cursor, recs);
        gather_csr_f32_kernel<<<N_ITEMS, 192, 0, stream>>>(E, keyA, recs, out);
    } else {
        float* deg = (float*)d_ws;
        hipMemsetAsync(deg, 0, (size_t)N_REL * N_ITEMS * sizeof(float), stream);
        {
            long long total = TOTAL_EDGES;
            int block = 256;
            long long grid = (total + block - 1) / block;
            deg_kernel<<<(unsigned)grid, block, 0, stream>>>(rows, vals, deg);
        }
        {
            int total = N_REL * N_ITEMS;
            int block = 256;
            int grid = (total + block - 1) / block;
            inv_kernel<<<grid, block, 0, stream>>>(deg);
        }
        hipMemcpyAsync(out, E, (size_t)N_ITEMS * EMBED_DIM * sizeof(float),
                       hipMemcpyDeviceToDevice, stream);
        {
            long long threads = (long long)TOTAL_EDGES * 64;
            int block = 256;
            long long grid = (threads + block - 1) / block;
            scatter_kernel<<<(unsigned)grid, block, 0, stream>>>(E, rows, cols, vals, deg, out);
        }
    }
}

// Round 9
// 369.600 us; speedup vs baseline: 1.9540x; 1.0028x over previous
//
#include <hip/hip_runtime.h>

// Problem constants (from reference)
#define N_ITEMS     100000
#define EMBED_DIM   64
#define N_REL       3
#define N_EDGES     3200000
#define TOTAL_EDGES (N_REL * N_EDGES)   // 9,600,000 (fits int)
#define NKEY        (N_REL * N_ITEMS)   // 300,000 (v5 fallback)

// == v17: v16 + 16B/lane vectorized partition loads (G13/m13: scalar streams
//    cap ~2 TB/s; float4/int4 streams reach 6.3 TB/s). Gather untouched. ==
#define LOG_CH   6
#define CH_ROWS  64
#define NCHUNK   1563                       // ceil(100000/64)
#define NBKT     (NCHUNK * N_REL)           // 4689
#define BCAP     2368                       // mean 2048 + ~7 sigma (proven R2-R8)
// Coarse buckets: 4096-row chunks; cursors RELATIVE to each rel's region.
#define LOG_CB   12
#define NCB      25                         // ceil(100000/4096)
#define TILEP    4096                       // staged tile (32KB+4KB LDS) — proven
#define NTILEP   ((N_EDGES + TILEP - 1) / TILEP)   // 782 tiles per rel
#define SEGSB    34
#define CBCAP    (SEGSB * TILEP)            // 139264 = mean 131072 + slack (proven)

// ---- v17.1: fused init (cursors) + vectorized E -> bf16 (v15-proven) ----
__global__ void init17_kernel(const float* __restrict__ E,
                              unsigned short* __restrict__ Ebf,
                              unsigned* __restrict__ gcursorF,
                              unsigned* __restrict__ cursorC) {
    int i = blockIdx.x * 256 + threadIdx.x;
    if (i < NBKT) gcursorF[i] = (unsigned)i * (unsigned)BCAP;
    if (i < N_REL * NCB) cursorC[i] = (unsigned)(i % NCB) * (unsigned)CBCAP;
    if (i < N_ITEMS * 16) {                 // 4 floats -> 4 bf16 per thread
        float4 f = ((const float4*)E)[i];
        unsigned u0 = __float_as_uint(f.x), u1 = __float_as_uint(f.y);
        unsigned u2 = __float_as_uint(f.z), u3 = __float_as_uint(f.w);
        ushort4 o;
        o.x = (unsigned short)((u0 + 0x7FFFu + ((u0 >> 16) & 1u)) >> 16);  // RNE
        o.y = (unsigned short)((u1 + 0x7FFFu + ((u1 >> 16) & 1u)) >> 16);
        o.z = (unsigned short)((u2 + 0x7FFFu + ((u2 >> 16) & 1u)) >> 16);
        o.w = (unsigned short)((u3 + 0x7FFFu + ((u3 >> 16) & 1u)) >> 16);
        ((ushort4*)Ebf)[i] = o;
    }
}

// ---- v17.2 pass A: int4/float4-staged partition into 25 coarse buckets ----
// Thread t owns edges [8t, 8t+8) of its tile (consecutive -> 16B/lane loads).
// Tile counts are multiples of 8, so activity is whole-thread.
// coarse rec: x = col(17b) | lrow12 << 17 ; y = val bits.
__launch_bounds__(512, 8)
__global__ void partA5_kernel(const int* __restrict__ rows,
                              const int* __restrict__ cols,
                              const float* __restrict__ vals,
                              unsigned* __restrict__ cursorC,
                              uint2* __restrict__ coarse,
                              int rel0, unsigned relStrideU2) {
    __shared__ uint2 stag[TILEP];              // 32 KB
    __shared__ unsigned char bkt[TILEP];       // 4 KB
    __shared__ unsigned hist[NCB], lstart[NCB], gbase[NCB], lcur[NCB];
    int rel = rel0 + blockIdx.x / NTILEP;
    int base = (blockIdx.x % NTILEP) * TILEP;
    int cnt = N_EDGES - base; if (cnt > TILEP) cnt = TILEP;
    int t = threadIdx.x;
    const int go = rel * N_EDGES + base;
    uint2* __restrict__ coarseRel = coarse + (size_t)(rel - rel0) * relStrideU2;

    // 16B/lane staging: 2x int4 rows + 2x int4 cols + 2x float4 vals
    unsigned rrow[8], rcol[8], rval[8];
    if ((t << 3) < cnt) {
        const int4*   r4 = (const int4*)(rows + go);
        const int4*   c4 = (const int4*)(cols + go);
        const float4* v4 = (const float4*)(vals + go);
        int4 ra = r4[2 * t], rb = r4[2 * t + 1];
        int4 ca = c4[2 * t], cc = c4[2 * t + 1];
        float4 va = v4[2 * t], vb = v4[2 * t + 1];
        rrow[0] = (unsigned)ra.x; rrow[1] = (unsigned)ra.y;
        rrow[2] = (unsigned)ra.z; rrow[3] = (unsigned)ra.w;
        rrow[4] = (unsigned)rb.x; rrow[5] = (unsigned)rb.y;
        rrow[6] = (unsigned)rb.z; rrow[7] = (unsigned)rb.w;
        rcol[0] = (unsigned)ca.x; rcol[1] = (unsigned)ca.y;
        rcol[2] = (unsigned)ca.z; rcol[3] = (unsigned)ca.w;
        rcol[4] = (unsigned)cc.x; rcol[5] = (unsigned)cc.y;
        rcol[6] = (unsigned)cc.z; rcol[7] = (unsigned)cc.w;
        rval[0] = __float_as_uint(va.x); rval[1] = __float_as_uint(va.y);
        rval[2] = __float_as_uint(va.z); rval[3] = __float_as_uint(va.w);
        rval[4] = __float_as_uint(vb.x); rval[5] = __float_as_uint(vb.y);
        rval[6] = __float_as_uint(vb.z); rval[7] = __float_as_uint(vb.w);
    } else {
        #pragma unroll
        for (int k = 0; k < 8; k++) rrow[k] = 0xFFFFFFFFu;
    }
    if (t < NCB) hist[t] = 0u;
    __syncthreads();
    #pragma unroll
    for (int k = 0; k < 8; k++)
        if (rrow[k] != 0xFFFFFFFFu) atomicAdd(&hist[rrow[k] >> LOG_CB], 1u);
    __syncthreads();
    if (t < 32) {                              // wave-parallel scan of 25 bins
        unsigned v = (t < NCB) ? hist[t] : 0u;
        unsigned inc = v;
        #pragma unroll
        for (int d = 1; d < 32; d <<= 1) {
            unsigned x = __shfl_up(inc, d, 32);
            if (t >= d) inc += x;
        }
        if (t < NCB) {
            unsigned ex = inc - v;
            lstart[t] = ex; lcur[t] = ex;
            if (v) gbase[t] = atomicAdd(&cursorC[rel * NCB + t], v);
        }
    }
    __syncthreads();
    #pragma unroll
    for (int k = 0; k < 8; k++)
        if (rrow[k] != 0xFFFFFFFFu) {
            unsigned row = rrow[k];
            unsigned cb = row >> LOG_CB;
            unsigned dst = atomicAdd(&lcur[cb], 1u);
            stag[dst] = make_uint2(rcol[k] | ((row & 4095u) << 17), rval[k]);
            bkt[dst] = (unsigned char)cb;
        }
    __syncthreads();
    // flush: consecutive staged slots of a bucket -> consecutive global slots
    for (int i = t; i < cnt; i += 512) {
        unsigned bb = bkt[i];
        unsigned dst = gbase[bb] + ((unsigned)i - lstart[bb]);
        if (dst < (bb + 1u) * (unsigned)CBCAP) coarseRel[dst] = stag[i];
    }
}

// ---- v17.3 pass B: uint4-staged refine into 64 fine buckets ----
// Thread t owns recs [8t, 8t+8) (consecutive -> 16B/lane loads, guarded tail).
// fine rec: x = col(17b) | lrow6 << 17 ; y = val bits.
__launch_bounds__(512, 8)
__global__ void partB5_kernel(const unsigned* __restrict__ cursorC,
                              const uint2* __restrict__ coarse,
                              unsigned* __restrict__ gcursorF,
                              uint2* __restrict__ recs,
                              int rel0, unsigned relStrideU2) {
    __shared__ uint2 stag[TILEP];              // 32 KB
    __shared__ unsigned char bkt[TILEP];       // 4 KB
    __shared__ unsigned hist[64], lstart[64], gbase[64], lcur[64];
    int rel = rel0 + blockIdx.x / (NCB * SEGSB);
    int rem = blockIdx.x % (NCB * SEGSB);
    int cb = rem / SEGSB, seg = rem % SEGSB;
    unsigned cntA = cursorC[rel * NCB + cb] - (unsigned)cb * (unsigned)CBCAP;
    if (cntA > (unsigned)CBCAP) cntA = (unsigned)CBCAP;
    int off = seg * TILEP;
    int cnt = (int)cntA - off;
    if (cnt <= 0) return;                      // block-uniform: no divergent barrier
    if (cnt > TILEP) cnt = TILEP;
    const uint2* __restrict__ src = coarse + (size_t)(rel - rel0) * relStrideU2
                                  + (unsigned)cb * (unsigned)CBCAP + off;
    int t = threadIdx.x;

    uint2 rc[8];
    int b8 = t << 3;
    if (b8 + 8 <= cnt) {                       // 4x uint4 = 16B/lane
        const uint4* s4 = (const uint4*)src;
        uint4 a = s4[4 * t],     b2 = s4[4 * t + 1];
        uint4 c2 = s4[4 * t + 2], d2 = s4[4 * t + 3];
        rc[0] = make_uint2(a.x, a.y);   rc[1] = make_uint2(a.z, a.w);
        rc[2] = make_uint2(b2.x, b2.y); rc[3] = make_uint2(b2.z, b2.w);
        rc[4] = make_uint2(c2.x, c2.y); rc[5] = make_uint2(c2.z, c2.w);
        rc[6] = make_uint2(d2.x, d2.y); rc[7] = make_uint2(d2.z, d2.w);
    } else {
        #pragma unroll
        for (int k = 0; k < 8; k++)
            rc[k] = (b8 + k < cnt) ? src[b8 + k] : make_uint2(0xFFFFFFFFu, 0u);
    }
    if (t < 64) hist[t] = 0u;
    __syncthreads();
    #pragma unroll
    for (int k = 0; k < 8; k++)
        if (rc[k].x != 0xFFFFFFFFu) atomicAdd(&hist[(rc[k].x >> 23) & 63u], 1u);
    __syncthreads();
    if (t < 64) {                              // wave0: full shfl scan of 64 bins
        unsigned v = hist[t];
        unsigned inc = v;
        #pragma unroll
        for (int d = 1; d < 64; d <<= 1) {
            unsigned x = __shfl_up(inc, d, 64);
            if (t >= d) inc += x;
        }
        unsigned ex = inc - v;
        lstart[t] = ex; lcur[t] = ex;
        if (v) gbase[t] = atomicAdd(&gcursorF[(((unsigned)cb << 6) + t) * 3u + rel], v);
    }
    __syncthreads();
    #pragma unroll
    for (int k = 0; k < 8; k++)
        if (rc[k].x != 0xFFFFFFFFu) {
            unsigned j = (rc[k].x >> 23) & 63u;
            unsigned dst = atomicAdd(&lcur[j], 1u);
            stag[dst] = make_uint2(rc[k].x & 0x7FFFFFu, rc[k].y);
            bkt[dst] = (unsigned char)j;
        }
    __syncthreads();
    for (int i = t; i < cnt; i += 512) {
        unsigned j = bkt[i];
        unsigned bf = (((unsigned)cb << 6) + j) * 3u + rel;
        unsigned dst = gbase[j] + ((unsigned)i - lstart[j]);
        if (dst < (bf + 1u) * (unsigned)BCAP) recs[dst] = stag[i];
    }
}

// ---- v17.4: fused count-sort + gather — BYTE-IDENTICAL to v12/v15/v16 (163 µs) ----
__launch_bounds__(512, 8)
__global__ void gather_sort_kernel(const uint2* __restrict__ Ebf4,   // ushort4 rows viewed as uint2
                                   const float* __restrict__ E,
                                   const unsigned* __restrict__ gcursorF,
                                   const uint2* __restrict__ recs,
                                   float* __restrict__ out) {
    __shared__ uint2  srt[BCAP];                 // 18.5 KB sorted records
    __shared__ float4 accT4[CH_ROWS * 16];       // 16 KB fp32 accumulation tile
    __shared__ unsigned hist[CH_ROWS], cur[CH_ROWS], rstart[CH_ROWS + 1];
    int c = blockIdx.x;
    int t = threadIdx.x;
    int w = t >> 6;            // wave 0..7 -> owns rows 8w..8w+7
    int lane = t & 63;
    int sub = lane >> 4;       // edge substream 0..3
    int q = lane & 15;         // dim quad (4q..4q+3)

    float* accT = (float*)accT4;
    for (int k = t; k < CH_ROWS * EMBED_DIM; k += 512) accT[k] = 0.f;

    for (int rel = 0; rel < N_REL; rel++) {
        unsigned b = (unsigned)(c * N_REL + rel);
        unsigned s0 = b * (unsigned)BCAP;
        int n = (int)(gcursorF[b] - s0);
        if (n > BCAP) n = BCAP;
        const uint2* __restrict__ pg = recs + s0;

        // register-stage this bucket's records (single global read)
        uint2 rc[5];
        #pragma unroll
        for (int k = 0; k < 5; k++) {
            int i = t + (k << 9);
            rc[k] = (i < n) ? pg[i] : make_uint2(0u, 0u);
        }
        if (t < CH_ROWS) hist[t] = 0u;
        __syncthreads();
        #pragma unroll
        for (int k = 0; k < 5; k++) {
            int i = t + (k << 9);
            if (i < n) atomicAdd(&hist[rc[k].x >> 17], 1u);
        }
        __syncthreads();
        if (t < 64) {                            // wave 0: exclusive scan of 64 bins
            unsigned v = hist[t];
            unsigned inc = v;
            #pragma unroll
            for (int d = 1; d < 64; d <<= 1) {
                unsigned x = __shfl_up(inc, d, 64);
                if (lane >= d) inc += x;
            }
            rstart[t] = inc - v;
            cur[t] = inc - v;
            if (t == 63) rstart[64] = inc;
        }
        __syncthreads();
        #pragma unroll
        for (int k = 0; k < 5; k++) {            // sort-scatter from registers
            int i = t + (k << 9);
            if (i < n) {
                unsigned pos = atomicAdd(&cur[rc[k].x >> 17], 1u);
                srt[pos] = make_uint2(rc[k].x & 0x1FFFFu, rc[k].y);
            }
        }
        __syncthreads();

        // ---- per-row register gather (R0-proven 16-lane x 4-substream, 4-deep) ----
        for (int k = 0; k < 8; k++) {
            int r = (w << 3) + k;
            int base = (int)rstart[r];
            int nr = (int)(rstart[r + 1] - rstart[r]);
            float a0 = 0.f, a1 = 0.f, a2 = 0.f, a3 = 0.f, dg = 0.f;
            int i = sub;
            for (; i + 12 < nr; i += 16) {       // 4 edges in flight per substream
                uint2 r0 = srt[base + i],     r1 = srt[base + i + 4];
                uint2 r2 = srt[base + i + 8], r3 = srt[base + i + 12];
                uint2 e0 = Ebf4[r0.x * 16u + q];
                uint2 e1 = Ebf4[r1.x * 16u + q];
                uint2 e2 = Ebf4[r2.x * 16u + q];
                uint2 e3 = Ebf4[r3.x * 16u + q];
                float w0 = __uint_as_float(r0.y), w1 = __uint_as_float(r1.y);
                float w2 = __uint_as_float(r2.y), w3 = __uint_as_float(r3.y);
                a0 += w0 * __uint_as_float(e0.x << 16);
                a1 += w0 * __uint_as_float(e0.x & 0xFFFF0000u);
                a2 += w0 * __uint_as_float(e0.y << 16);
                a3 += w0 * __uint_as_float(e0.y & 0xFFFF0000u);
                dg += w0;
                a0 += w1 * __uint_as_float(e1.x << 16);
                a1 += w1 * __uint_as_float(e1.x & 0xFFFF0000u);
                a2 += w1 * __uint_as_float(e1.y << 16);
                a3 += w1 * __uint_as_float(e1.y & 0xFFFF0000u);
                dg += w1;
                a0 += w2 * __uint_as_float(e2.x << 16);
                a1 += w2 * __uint_as_float(e2.x & 0xFFFF0000u);
                a2 += w2 * __uint_as_float(e2.y << 16);
                a3 += w2 * __uint_as_float(e2.y & 0xFFFF0000u);
                dg += w2;
                a0 += w3 * __uint_as_float(e3.x << 16);
                a1 += w3 * __uint_as_float(e3.x & 0xFFFF0000u);
                a2 += w3 * __uint_as_float(e3.y << 16);
                a3 += w3 * __uint_as_float(e3.y & 0xFFFF0000u);
                dg += w3;
            }
            for (; i < nr; i += 4) {
                uint2 r0 = srt[base + i];
                uint2 e0 = Ebf4[r0.x * 16u + q];
                float w0 = __uint_as_float(r0.y);
                a0 += w0 * __uint_as_float(e0.x << 16);
                a1 += w0 * __uint_as_float(e0.x & 0xFFFF0000u);
                a2 += w0 * __uint_as_float(e0.y << 16);
                a3 += w0 * __uint_as_float(e0.y & 0xFFFF0000u);
                dg += w0;
            }
            // combine 4 substreams (lanes differing in bits 4,5)
            a0 += __shfl_xor(a0, 16, 64);  a0 += __shfl_xor(a0, 32, 64);
            a1 += __shfl_xor(a1, 16, 64);  a1 += __shfl_xor(a1, 32, 64);
            a2 += __shfl_xor(a2, 16, 64);  a2 += __shfl_xor(a2, 32, 64);
            a3 += __shfl_xor(a3, 16, 64);  a3 += __shfl_xor(a3, 32, 64);
            dg += __shfl_xor(dg, 16, 64);  dg += __shfl_xor(dg, 32, 64);
            float inv = 1.0f / (3.0f * fmaxf(dg, 1.0f));
            if (sub == 0) {                      // exclusive owner: plain RMW
                float4 o = accT4[(r << 4) + q];
                accT4[(r << 4) + q] = make_float4(o.x + a0 * inv, o.y + a1 * inv,
                                                  o.z + a2 * inv, o.w + a3 * inv);
            }
        }
        __syncthreads();                         // srt/hist reuse next rel
    }

    int gbase2 = c * (CH_ROWS * EMBED_DIM);
    for (int k = t; k < CH_ROWS * EMBED_DIM; k += 512) {
        int gi = gbase2 + k;
        if (gi < N_ITEMS * EMBED_DIM) out[gi] = E[gi] + accT[k];
    }
}

// ============================ v5 fallback (R5 pipeline) ============================
#define NBS ((NKEY + 255) / 256)

__global__ void hist300_kernel(const int* __restrict__ rows, unsigned* __restrict__ cnt) {
    int stride = gridDim.x * blockDim.x;
    for (int i = blockIdx.x * blockDim.x + threadIdx.x; i < TOTAL_EDGES; i += stride) {
        unsigned r = (unsigned)i / (unsigned)N_EDGES;
        unsigned key = r * N_ITEMS + (unsigned)rows[i];
        atomicAdd(&cnt[key], 1u);
    }
}

__global__ void scan_blocksum(const unsigned* __restrict__ cnt, unsigned* __restrict__ bsum) {
    __shared__ unsigned s[256];
    int i = blockIdx.x * 256 + threadIdx.x;
    s[threadIdx.x] = (i < NKEY) ? cnt[i] : 0u;
    __syncthreads();
    for (int off = 128; off > 0; off >>= 1) {
        if (threadIdx.x < off) s[threadIdx.x] += s[threadIdx.x + off];
        __syncthreads();
    }
    if (threadIdx.x == 0) bsum[blockIdx.x] = s[0];
}

__global__ void scan_partials(unsigned* __restrict__ bsum, unsigned* __restrict__ starts) {
    const int IT = 5;
    int t = threadIdx.x;
    unsigned loc[IT];
    unsigned sum = 0;
    #pragma unroll
    for (int k = 0; k < IT; k++) {
        int idx = t * IT + k;
        loc[k] = (idx < NBS) ? bsum[idx] : 0u;
        sum += loc[k];
    }
    int lane = t & 63, wid = t >> 6;
    unsigned inc = sum;
    #pragma unroll
    for (int d = 1; d < 64; d <<= 1) {
        unsigned x = __shfl_up(inc, d, 64);
        if (lane >= d) inc += x;
    }
    __shared__ unsigned woff[4], woffEx[4];
    if (lane == 63) woff[wid] = inc;
    __syncthreads();
    if (t == 0) { unsigned run = 0; for (int k = 0; k < 4; k++) { woffEx[k] = run; run += woff[k]; } }
    __syncthreads();
    unsigned ex = inc - sum + woffEx[wid];
    #pragma unroll
    for (int k = 0; k < IT; k++) {
        int idx = t * IT + k;
        if (idx < NBS) { bsum[idx] = ex; ex += loc[k]; }
    }
    if (t == 0) starts[NKEY] = (unsigned)TOTAL_EDGES;
}

__global__ void scan_final(unsigned* key_arr,
                           const unsigned* __restrict__ bsum,
                           unsigned* __restrict__ cursor) {
    int i = blockIdx.x * 256 + threadIdx.x;
    unsigned v = (i < NKEY) ? key_arr[i] : 0u;
    int lane = threadIdx.x & 63, wid = threadIdx.x >> 6;
    unsigned inc = v;
    #pragma unroll
    for (int d = 1; d < 64; d <<= 1) {
        unsigned x = __shfl_up(inc, d, 64);
        if (lane >= d) inc += x;
    }
    __shared__ unsigned woff[4], woffEx[4];
    if (lane == 63) woff[wid] = inc;
    __syncthreads();
    if (threadIdx.x == 0) { unsigned run = 0; for (int k = 0; k < 4; k++) { woffEx[k] = run; run += woff[k]; } }
    __syncthreads();
    unsigned ex = inc - v + woffEx[wid] + bsum[blockIdx.x];
    if (i < NKEY) { key_arr[i] = ex; cursor[i] = ex; }
}

__global__ void binscatter2_kernel(const int* __restrict__ rows,
                                   const int* __restrict__ cols,
                                   const float* __restrict__ vals,
                                   unsigned* __restrict__ cursor,
                                   uint2* __restrict__ recs) {
    int stride = gridDim.x * blockDim.x;
    for (int i = blockIdx.x * blockDim.x + threadIdx.x; i < TOTAL_EDGES; i += stride) {
        unsigned r = (unsigned)i / (unsigned)N_EDGES;
        unsigned key = r * N_ITEMS + (unsigned)rows[i];
        unsigned pos = atomicAdd(&cursor[key], 1u);
        uint2 rec;
        rec.x = (unsigned)cols[i];
        rec.y = __float_as_uint(vals[i]);
        recs[pos] = rec;
    }
}

__launch_bounds__(192)
__global__ void gather_csr_f32_kernel(const float* __restrict__ E,
                                      const unsigned* __restrict__ starts,
                                      const uint2* __restrict__ recs,
                                      float* __restrict__ out) {
    __shared__ float part[N_REL * EMBED_DIM];
    int row = blockIdx.x;
    int w = threadIdx.x >> 6;
    int d = threadIdx.x & 63;
    unsigned key = (unsigned)w * N_ITEMS + (unsigned)row;
    unsigned s = starts[key];
    int n = (int)(starts[key + 1] - s);
    const uint2* __restrict__ p = recs + s;
    float acc = 0.0f, deg = 0.0f;
    int j = 0;
    for (; j + 8 <= n; j += 8) {
        uint2 a[8];
        #pragma unroll
        for (int k = 0; k < 8; k++) a[k] = p[j + k];
        float e[8];
        #pragma unroll
        for (int k = 0; k < 8; k++) e[k] = E[a[k].x * EMBED_DIM + d];
        #pragma unroll
        for (int k = 0; k < 8; k++) {
            float wv = __uint_as_float(a[k].y);
            acc += wv * e[k];
            deg += wv;
        }
    }
    for (; j < n; j++) {
        uint2 a = p[j];
        float wv = __uint_as_float(a.y);
        acc += wv * E[a.x * EMBED_DIM + d];
        deg += wv;
    }
    part[w * EMBED_DIM + d] = acc / (3.0f * fmaxf(deg, 1.0f));
    __syncthreads();
    if (threadIdx.x < EMBED_DIM) {
        int gi = row * EMBED_DIM + threadIdx.x;
        out[gi] = E[gi] + part[threadIdx.x]
                        + part[EMBED_DIM + threadIdx.x]
                        + part[2 * EMBED_DIM + threadIdx.x];
    }
}

// ============================ R1 fallback ============================
__global__ void deg_kernel(const int* __restrict__ rows,
                           const float* __restrict__ vals,
                           float* __restrict__ deg) {
    long long i = (long long)blockIdx.x * blockDim.x + threadIdx.x;
    if (i >= TOTAL_EDGES) return;
    int r = (int)(i / N_EDGES);
    int row = rows[i];
    atomicAdd(&deg[(long long)r * N_ITEMS + row], vals[i]);
}

__global__ void inv_kernel(float* __restrict__ deg) {
    int i = blockIdx.x * blockDim.x + threadIdx.x;
    if (i >= N_REL * N_ITEMS) return;
    float d = deg[i];
    d = fmaxf(d, 1.0f);
    deg[i] = 1.0f / (3.0f * d);
}

__global__ void scatter_kernel(const float* __restrict__ E,
                               const int* __restrict__ rows,
                               const int* __restrict__ cols,
                               const float* __restrict__ vals,
                               const float* __restrict__ inv,
                               float* __restrict__ out) {
    long long t = (long long)blockIdx.x * blockDim.x + threadIdx.x;
    long long edge = t >> 6;
    int d = (int)(t & 63);
    if (edge >= TOTAL_EDGES) return;
    int r = (int)(edge / N_EDGES);
    int row = rows[edge];
    int col = cols[edge];
    float w = vals[edge] * inv[r * N_ITEMS + row];
    float msg = w * E[(long long)col * EMBED_DIM + d];
    atomicAdd(&out[(long long)row * EMBED_DIM + d], msg);
}

// ============================ launcher ============================
extern "C" void kernel_launch(void* const* d_in, const int* in_sizes, int n_in,
                              void* d_out, int out_size, void* d_ws, size_t ws_size,
                              hipStream_t stream) {
    const float* E    = (const float*)d_in[0];
    const int*   rows = (const int*)d_in[1];
    const int*   cols = (const int*)d_in[2];
    const float* vals = (const float*)d_in[3];
    float* out = (float*)d_out;

    // v17 workspace: [GC 32KB: gcursorF@0, cursorC@20480] | coarse (1 or 3 rel
    // regions) | fine recs | Ebf
    const size_t GCB      = 32768;
    const size_t COARSE1  = (size_t)NCB * CBCAP * sizeof(uint2);    // 27.85 MB / rel
    const size_t FINE_B   = (size_t)NBKT * BCAP * sizeof(uint2);    // 88.83 MB
    const size_t EBF_B    = (size_t)N_ITEMS * EMBED_DIM * 2;        // 12.8 MB
    size_t need17 = GCB + 3 * COARSE1 + FINE_B + EBF_B;             // ~185.2 MB (proven fits R4-R8)
    size_t need11 = GCB + COARSE1 + FINE_B + EBF_B;                 // ~129.5 MB (proven fits)

    // v5 fallback sizes
    const size_t REGA = 1204224;                                    // >= (NKEY+1)*4
    const size_t REGC = 8192;
    const size_t RECB = (size_t)TOTAL_EDGES * sizeof(uint2);        // 76.8 MB
    size_t need5 = 2 * REGA + REGC + RECB;

    int initGrid = (N_ITEMS * 16 + 255) / 256;

    if (ws_size >= need17) {
        // fused 3-rel partition: 2 launches
        unsigned* gcursorF = (unsigned*)d_ws;
        unsigned* cursorC  = (unsigned*)((char*)d_ws + 20480);
        uint2*    coarse   = (uint2*)((char*)d_ws + GCB);
        uint2*    recs     = (uint2*)((char*)d_ws + GCB + 3 * COARSE1);
        unsigned short* Ebf = (unsigned short*)((char*)d_ws + GCB + 3 * COARSE1 + FINE_B);

        init17_kernel<<<initGrid, 256, 0, stream>>>(E, Ebf, gcursorF, cursorC);
        partA5_kernel<<<N_REL * NTILEP, 512, 0, stream>>>(
            rows, cols, vals, cursorC, coarse, 0, (unsigned)(NCB * CBCAP));
        partB5_kernel<<<N_REL * NCB * SEGSB, 512, 0, stream>>>(
            cursorC, coarse, gcursorF, recs, 0, (unsigned)(NCB * CBCAP));
        gather_sort_kernel<<<NCHUNK, 512, 0, stream>>>((const uint2*)Ebf, E, gcursorF, recs, out);
    } else if (ws_size >= need11) {
        // per-rel loop, coarse buffer reused (proven layout)
        unsigned* gcursorF = (unsigned*)d_ws;
        unsigned* cursorC  = (unsigned*)((char*)d_ws + 20480);
        uint2*    coarse   = (uint2*)((char*)d_ws + GCB);
        uint2*    recs     = (uint2*)((char*)d_ws + GCB + COARSE1);
        unsigned short* Ebf = (unsigned short*)((char*)d_ws + GCB + COARSE1 + FINE_B);

        init17_kernel<<<initGrid, 256, 0, stream>>>(E, Ebf, gcursorF, cursorC);
        for (int r = 0; r < N_REL; r++) {
            partA5_kernel<<<NTILEP, 512, 0, stream>>>(
                rows, cols, vals, cursorC, coarse, r, 0u);
            partB5_kernel<<<NCB * SEGSB, 512, 0, stream>>>(
                cursorC, coarse, gcursorF, recs, r, 0u);
        }
        gather_sort_kernel<<<NCHUNK, 512, 0, stream>>>((const uint2*)Ebf, E, gcursorF, recs, out);
    } else if (ws_size >= need5) {
        unsigned* keyA   = (unsigned*)d_ws;
        unsigned* cursor = (unsigned*)((char*)d_ws + REGA);
        unsigned* bsum   = (unsigned*)((char*)d_ws + 2 * REGA);
        uint2*    recs   = (uint2*)((char*)d_ws + 2 * REGA + REGC);

        hipMemsetAsync(keyA, 0, NKEY * sizeof(unsigned), stream);
        hist300_kernel<<<1536, 256, 0, stream>>>(rows, keyA);
        scan_blocksum<<<NBS, 256, 0, stream>>>(keyA, bsum);
        scan_partials<<<1, 256, 0, stream>>>(bsum, keyA);
        scan_final<<<NBS, 256, 0, stream>>>(keyA, bsum, cursor);
        binscatter2_kernel<<<2048, 256, 0, stream>>>(rows, cols, vals, cursor, recs);
        gather_csr_f32_kernel<<<N_ITEMS, 192, 0, stream>>>(E, keyA, recs, out);
    } else {
        float* deg = (float*)d_ws;
        hipMemsetAsync(deg, 0, (size_t)N_REL * N_ITEMS * sizeof(float), stream);
        {
            long long total = TOTAL_EDGES;
            int block = 256;
            long long grid = (total + block - 1) / block;
            deg_kernel<<<(unsigned)grid, block, 0, stream>>>(rows, vals, deg);
        }
        {
            int total = N_REL * N_ITEMS;
            int block = 256;
            int grid = (total + block - 1) / block;
            inv_kernel<<<grid, block, 0, stream>>>(deg);
        }
        hipMemcpyAsync(out, E, (size_t)N_ITEMS * EMBED_DIM * sizeof(float),
                       hipMemcpyDeviceToDevice, stream);
        {
            long long threads = (long long)TOTAL_EDGES * 64;
            int block = 256;
            long long grid = (threads + block - 1) / block;
            scatter_kernel<<<(unsigned)grid, block, 0, stream>>>(E, rows, cols, vals, deg, out);
        }
    }
}